// Round 1
// baseline (1570.236 us; speedup 1.0000x reference)
//
#include <hip/hip_runtime.h>
#include <math.h>

#define DEVI static __device__ __forceinline__

DEVI float gelu_f(float x) {
    return 0.5f * x * (1.0f + erff(x * 0.7071067811865475f));
}
DEVI void fmadd4(float4& acc, const float4& a, const float4& b) {
    acc.x = fmaf(a.x, b.x, acc.x);
    acc.y = fmaf(a.y, b.y, acc.y);
    acc.z = fmaf(a.z, b.z, acc.z);
    acc.w = fmaf(a.w, b.w, acc.w);
}
DEVI void fmas4(float4& acc, float p, const float4& v) {
    acc.x = fmaf(p, v.x, acc.x);
    acc.y = fmaf(p, v.y, acc.y);
    acc.z = fmaf(p, v.z, acc.z);
    acc.w = fmaf(p, v.w, acc.w);
}
DEVI float hsum4(const float4& v) { return (v.x + v.y) + (v.z + v.w); }

// ---------------------------------------------------------------------------
// Generic fp32 GEMM: C[M,N] = act( A[M,K] (*amask per-batch col) @ B + bias )
// BT=true:  B stored [N,K] (i.e. Y = X @ W^T, both K-contiguous)
// BT=false: B stored [K,N]
// amask (nullable): [B][K] row-mask applied to A columns, batch = row>>10 (S=1024)
// ---------------------------------------------------------------------------
template<bool BT, bool DO_GELU>
__global__ __launch_bounds__(256)
void gemm_kernel(const float* __restrict__ A, const float* __restrict__ Bm,
                 const float* __restrict__ bias, const float* __restrict__ amask,
                 float* __restrict__ C, int M, int N, int K)
{
    __shared__ float As[16][68];
    __shared__ float Bs[16][68];
    const int t  = threadIdx.x;
    const int tx = t & 15, ty = t >> 4;
    const int m0 = blockIdx.y * 64, n0 = blockIdx.x * 64;
    const int r  = t >> 2, c4 = t & 3;   // A (and BT-B) load mapping
    const int kb = t >> 4, cb = t & 15;  // non-BT B load mapping
    float acc[4][4] = {};
    for (int k0 = 0; k0 < K; k0 += 16) {
        float4 av = *(const float4*)&A[(size_t)(m0 + r) * K + (k0 + c4 * 4)];
        if (amask) {
            const float* mr = amask + (size_t)((m0 + r) >> 10) * K + (k0 + c4 * 4);
            av.x *= mr[0]; av.y *= mr[1]; av.z *= mr[2]; av.w *= mr[3];
        }
        float4 bv;
        if (BT) bv = *(const float4*)&Bm[(size_t)(n0 + r) * K + (k0 + c4 * 4)];
        else    bv = *(const float4*)&Bm[(size_t)(k0 + kb) * N + (n0 + cb * 4)];
        __syncthreads();   // previous tile fully consumed before overwrite
        As[c4 * 4 + 0][r] = av.x;
        As[c4 * 4 + 1][r] = av.y;
        As[c4 * 4 + 2][r] = av.z;
        As[c4 * 4 + 3][r] = av.w;
        if (BT) {
            Bs[c4 * 4 + 0][r] = bv.x;
            Bs[c4 * 4 + 1][r] = bv.y;
            Bs[c4 * 4 + 2][r] = bv.z;
            Bs[c4 * 4 + 3][r] = bv.w;
        } else {
            *(float4*)&Bs[kb][cb * 4] = bv;
        }
        __syncthreads();
        #pragma unroll
        for (int kk = 0; kk < 16; ++kk) {
            float4 a4 = *(const float4*)&As[kk][ty * 4];
            float4 b4 = *(const float4*)&Bs[kk][tx * 4];
            acc[0][0] = fmaf(a4.x, b4.x, acc[0][0]);
            acc[0][1] = fmaf(a4.x, b4.y, acc[0][1]);
            acc[0][2] = fmaf(a4.x, b4.z, acc[0][2]);
            acc[0][3] = fmaf(a4.x, b4.w, acc[0][3]);
            acc[1][0] = fmaf(a4.y, b4.x, acc[1][0]);
            acc[1][1] = fmaf(a4.y, b4.y, acc[1][1]);
            acc[1][2] = fmaf(a4.y, b4.z, acc[1][2]);
            acc[1][3] = fmaf(a4.y, b4.w, acc[1][3]);
            acc[2][0] = fmaf(a4.z, b4.x, acc[2][0]);
            acc[2][1] = fmaf(a4.z, b4.y, acc[2][1]);
            acc[2][2] = fmaf(a4.z, b4.z, acc[2][2]);
            acc[2][3] = fmaf(a4.z, b4.w, acc[2][3]);
            acc[3][0] = fmaf(a4.w, b4.x, acc[3][0]);
            acc[3][1] = fmaf(a4.w, b4.y, acc[3][1]);
            acc[3][2] = fmaf(a4.w, b4.z, acc[3][2]);
            acc[3][3] = fmaf(a4.w, b4.w, acc[3][3]);
        }
    }
    #pragma unroll
    for (int i = 0; i < 4; ++i) {
        float4 o;
        o.x = acc[i][0]; o.y = acc[i][1]; o.z = acc[i][2]; o.w = acc[i][3];
        if (bias) {
            const float* bb = bias + n0 + tx * 4;
            o.x += bb[0]; o.y += bb[1]; o.z += bb[2]; o.w += bb[3];
        }
        if (DO_GELU) {
            o.x = gelu_f(o.x); o.y = gelu_f(o.y); o.z = gelu_f(o.z); o.w = gelu_f(o.w);
        }
        *(float4*)&C[(size_t)(m0 + ty * 4 + i) * N + (n0 + tx * 4)] = o;
    }
}

// ---------------------------------------------------------------------------
// Streaming MHA, head_dim = 128 fixed, S = 1024. No max-subtraction (scores
// are tiny: |s*scale| << 10). One block = one (b,h) x 64 q-rows.
// Thread t: rows {rp, rp+32} (rp=t>>3), key pair {2g, 2g+1} / d-cols
// {32q + 4g .. +3} (g=t&7).
// ---------------------------------------------------------------------------
__global__ __launch_bounds__(256)
void attn_kernel(const float* __restrict__ Q, const float* __restrict__ K,
                 const float* __restrict__ V, float* __restrict__ O,
                 int S, int Dm, int H, float scale)
{
    __shared__ float Qs[64][132];
    __shared__ float Ks[16][132];
    __shared__ float Vs[16][132];
    __shared__ float Ps[64][17];
    __shared__ float Ls[64];
    const int t  = threadIdx.x;
    const int b  = blockIdx.y / H, h = blockIdx.y % H;
    const int s0 = blockIdx.x * 64;
    const float* Qb = Q + (size_t)b * S * Dm + h * 128;
    const float* Kb = K + (size_t)b * S * Dm + h * 128;
    const float* Vb = V + (size_t)b * S * Dm + h * 128;
    #pragma unroll
    for (int i = 0; i < 8; ++i) {
        int f = t + i * 256;
        int row = f >> 5, c = f & 31;
        *(float4*)&Qs[row][c * 4] = *(const float4*)&Qb[(size_t)(s0 + row) * Dm + c * 4];
    }
    const int rp = t >> 3;
    const int g  = t & 7;
    float4 acc0[4] = {};
    float4 acc1[4] = {};
    float l0 = 0.f, l1 = 0.f;
    for (int c0 = 0; c0 < S; c0 += 16) {
        __syncthreads();  // previous chunk fully consumed
        #pragma unroll
        for (int i = 0; i < 2; ++i) {
            int f = t + i * 256;
            int row = f >> 5, c = f & 31;
            *(float4*)&Ks[row][c * 4] = *(const float4*)&Kb[(size_t)(c0 + row) * Dm + c * 4];
            *(float4*)&Vs[row][c * 4] = *(const float4*)&Vb[(size_t)(c0 + row) * Dm + c * 4];
        }
        __syncthreads();
        float4 s00 = {}, s01 = {}, s10 = {}, s11 = {};
        #pragma unroll 8
        for (int d4 = 0; d4 < 32; ++d4) {
            float4 q0 = *(const float4*)&Qs[rp][d4 * 4];
            float4 q1 = *(const float4*)&Qs[rp + 32][d4 * 4];
            float4 k0 = *(const float4*)&Ks[2 * g][d4 * 4];
            float4 k1 = *(const float4*)&Ks[2 * g + 1][d4 * 4];
            fmadd4(s00, q0, k0); fmadd4(s01, q0, k1);
            fmadd4(s10, q1, k0); fmadd4(s11, q1, k1);
        }
        float p00 = __expf(hsum4(s00) * scale);
        float p01 = __expf(hsum4(s01) * scale);
        float p10 = __expf(hsum4(s10) * scale);
        float p11 = __expf(hsum4(s11) * scale);
        Ps[rp][2 * g]      = p00; Ps[rp][2 * g + 1]      = p01;
        Ps[rp + 32][2 * g] = p10; Ps[rp + 32][2 * g + 1] = p11;
        l0 += p00 + p01; l1 += p10 + p11;
        __syncthreads();
        #pragma unroll 4
        for (int j = 0; j < 16; ++j) {
            float pj0 = Ps[rp][j], pj1 = Ps[rp + 32][j];
            #pragma unroll
            for (int q = 0; q < 4; ++q) {
                float4 v4 = *(const float4*)&Vs[j][q * 32 + g * 4];
                fmas4(acc0[q], pj0, v4);
                fmas4(acc1[q], pj1, v4);
            }
        }
    }
    #pragma unroll
    for (int off = 1; off < 8; off <<= 1) {
        l0 += __shfl_xor(l0, off, 64);
        l1 += __shfl_xor(l1, off, 64);
    }
    if (g == 0) { Ls[rp] = l0; Ls[rp + 32] = l1; }
    __syncthreads();
    float inv0 = 1.0f / Ls[rp], inv1 = 1.0f / Ls[rp + 32];
    float* Ob0 = O + (size_t)(b * S + s0 + rp) * Dm + h * 128;
    float* Ob1 = O + (size_t)(b * S + s0 + rp + 32) * Dm + h * 128;
    #pragma unroll
    for (int q = 0; q < 4; ++q) {
        float4 o0, o1;
        o0.x = acc0[q].x * inv0; o0.y = acc0[q].y * inv0;
        o0.z = acc0[q].z * inv0; o0.w = acc0[q].w * inv0;
        o1.x = acc1[q].x * inv1; o1.y = acc1[q].y * inv1;
        o1.z = acc1[q].z * inv1; o1.w = acc1[q].w * inv1;
        *(float4*)&Ob0[q * 32 + g * 4] = o0;
        *(float4*)&Ob1[q * 32 + g * 4] = o1;
    }
}

// ---------------------------------------------------------------------------
// Reduce over S (axis=1) of X[B,S,N]. OP: 0=max, 1=sum. Two stages.
// ---------------------------------------------------------------------------
template<int OP>
__global__ __launch_bounds__(256)
void reduce_stage1(const float* __restrict__ X, float* __restrict__ P, int S, int N)
{
    int n  = blockIdx.x * 256 + threadIdx.x;
    int sc = blockIdx.y;
    int b  = blockIdx.z;
    const float* base = X + ((size_t)b * S + sc * 64) * N + n;
    float acc = (OP == 0) ? -3.402823466e38f : 0.f;
    for (int s = 0; s < 64; ++s) {
        float v = base[(size_t)s * N];
        acc = (OP == 0) ? fmaxf(acc, v) : (acc + v);
    }
    P[((size_t)b * 16 + sc) * N + n] = acc;
}

template<int OP>
__global__ __launch_bounds__(256)
void reduce_stage2(const float* __restrict__ P, float* __restrict__ Y, int N, float scl)
{
    int n = blockIdx.x * 256 + threadIdx.x;
    int b = blockIdx.y;
    float acc = (OP == 0) ? -3.402823466e38f : 0.f;
    for (int s = 0; s < 16; ++s) {
        float v = P[((size_t)b * 16 + s) * N + n];
        acc = (OP == 0) ? fmaxf(acc, v) : (acc + v);
    }
    Y[(size_t)b * N + n] = (OP == 0) ? acc : acc * scl;
}

// ---------------------------------------------------------------------------
// Top-K -> 0/1 mask. Bitonic sort in LDS, descending by value, ties: lower
// index first (matches jax.lax.top_k). Block = N threads, grid = B.
// ---------------------------------------------------------------------------
template<int N, int KSEL>
__global__ __launch_bounds__(1024)
void topk_mask_kernel(const float* __restrict__ Sc, float* __restrict__ mask)
{
    __shared__ float v[N];
    __shared__ int   id[N];
    int t = threadIdx.x;
    int b = blockIdx.x;
    v[t]  = Sc[b * N + t];
    id[t] = t;
    __syncthreads();
    for (int k = 2; k <= N; k <<= 1) {
        for (int j = k >> 1; j > 0; j >>= 1) {
            int ixj = t ^ j;
            if (ixj > t) {
                bool dir = ((t & k) == 0);  // true -> descending segment
                float va = v[t], vb = v[ixj];
                int   ia = id[t], ib = id[ixj];
                // e[ixj] strictly "before" e[t] in (val desc, idx asc) order?
                bool before_b = (vb > va) || (vb == va && ib < ia);
                bool sw = dir ? before_b : !before_b;
                if (sw) { v[t] = vb; v[ixj] = va; id[t] = ib; id[ixj] = ia; }
            }
            __syncthreads();
        }
    }
    mask[b * N + id[t]] = (t < KSEL) ? 1.0f : 0.0f;
}

// ---------------------------------------------------------------------------
// y = LayerNorm(x + r) * gamma + beta, then * mask[b][n].  N = 512 fixed.
// ---------------------------------------------------------------------------
__global__ __launch_bounds__(256)
void ln_mask_kernel(const float* __restrict__ X, const float* __restrict__ R,
                    const float* __restrict__ gam, const float* __restrict__ bet,
                    const float* __restrict__ mask, float* __restrict__ Y, int N)
{
    int row = blockIdx.x;         // b*S + s, S=1024
    int b   = row >> 10;
    int t   = threadIdx.x;
    const float* x0 = X + (size_t)row * N;
    const float* r0 = R + (size_t)row * N;
    float a1 = x0[t] + r0[t];
    float a2 = x0[t + 256] + r0[t + 256];
    float s  = a1 + a2;
    float sq = a1 * a1 + a2 * a2;
    #pragma unroll
    for (int off = 32; off > 0; off >>= 1) {
        s  += __shfl_down(s, off, 64);
        sq += __shfl_down(sq, off, 64);
    }
    __shared__ float red[8];
    int wid = t >> 6, lane = t & 63;
    if (lane == 0) { red[wid] = s; red[wid + 4] = sq; }
    __syncthreads();
    if (t == 0) {
        float st  = red[0] + red[1] + red[2] + red[3];
        float sqt = red[4] + red[5] + red[6] + red[7];
        float mu  = st / (float)N;
        float var = sqt / (float)N - mu * mu;
        red[0] = mu;
        red[1] = rsqrtf(var + 1e-5f);
    }
    __syncthreads();
    float mu = red[0], rstd = red[1];
    float y1 = (a1 - mu) * rstd * gam[t] + bet[t];
    float y2 = (a2 - mu) * rstd * gam[t + 256] + bet[t + 256];
    Y[(size_t)row * N + t]       = y1 * mask[b * N + t];
    Y[(size_t)row * N + t + 256] = y2 * mask[b * N + t + 256];
}

// ---------------------------------------------------------------------------
extern "C" void kernel_launch(void* const* d_in, const int* in_sizes, int n_in,
                              void* d_out, int out_size, void* d_ws, size_t ws_size,
                              hipStream_t stream)
{
    (void)in_sizes; (void)n_in; (void)out_size; (void)ws_size;
    const float* x        = (const float*)d_in[0];
    const float* r_wq     = (const float*)d_in[1];
    const float* r_wk     = (const float*)d_in[2];
    const float* r_wv     = (const float*)d_in[3];
    const float* r_bq     = (const float*)d_in[4];
    const float* r_bk     = (const float*)d_in[5];
    const float* r_bv     = (const float*)d_in[6];
    const float* r_wo     = (const float*)d_in[7];
    const float* r_bo     = (const float*)d_in[8];
    const float* aff_w    = (const float*)d_in[9];
    const float* aff_b    = (const float*)d_in[10];
    const float* patterns = (const float*)d_in[11];
    const float* i_wq     = (const float*)d_in[12];
    const float* i_wk     = (const float*)d_in[13];
    const float* i_wv     = (const float*)d_in[14];
    const float* i_bq     = (const float*)d_in[15];
    const float* i_bk     = (const float*)d_in[16];
    const float* i_bv     = (const float*)d_in[17];
    const float* i_wo     = (const float*)d_in[18];
    const float* i_bo     = (const float*)d_in[19];
    const float* ln_g     = (const float*)d_in[20];
    const float* ln_b     = (const float*)d_in[21];
    const float* comb_w   = (const float*)d_in[22];
    const float* proj_w   = (const float*)d_in[23];
    // d_in[24]=k_input(256), d_in[25]=k_process(512): hardcoded in templates.

    constexpr int B = 4, S = 1024, D = 1024, NI = 512, NP = 1024;
    constexpr int M = B * S;
    constexpr size_t R4M = 4194304;   // 4M floats
    constexpr size_t R2M = 2097152;

    float* W   = (float*)d_ws;
    float* rq  = W;              // router Q    [4M]  -> later: pa [4M]
    float* rk  = W + R4M;        // router K    [4M]  -> affinity[2M] -> iq/ik -> a2f
    float* rv  = W + 2 * R4M;    // router V    [4M]  -> iv[2M], a2p[2M]
    float* ap  = W + 3 * R4M;    // router attn pre-proj [4M] -> act[2M], lnm[2M]
    float* ctx = W + 4 * R4M;    // context     [4M]
    float* aff = rk;             // [B,S,NI] 2M
    float* iq  = rk;             // [2M] (after scores consumed affinity)
    float* ik  = rk + R2M;       // [2M]
    float* iv  = rv;             // [2M]
    float* a2p = rv + R2M;       // [2M] input-attn pre-proj
    float* a2f = rk;             // [2M] input-attn final (iq dead by then)
    float* act = ap;             // [2M]
    float* lnm = ap + R2M;       // [2M] layernorm'd + masked act
    float* pa  = rq;             // [4M]
    float* sm      = W + 5 * R4M;
    float* partial = sm;                 // up to B*16*1024 = 65536
    float* scores  = sm + 65536;         // B*512
    float* maskI   = sm + 67584;         // B*512
    float* ps      = sm + 69632;         // B*1024
    float* maskP   = sm + 73728;         // B*1024

    const float scale = 0.08838834764831843f;  // 1/sqrt(128)
    dim3 blk(256);

    // --- DynamicRouter MHA ---
    gemm_kernel<true,  false><<<dim3(D / 64, M / 64), blk, 0, stream>>>(x, r_wq, r_bq, nullptr, rq, M, D, D);
    gemm_kernel<true,  false><<<dim3(D / 64, M / 64), blk, 0, stream>>>(x, r_wk, r_bk, nullptr, rk, M, D, D);
    gemm_kernel<true,  false><<<dim3(D / 64, M / 64), blk, 0, stream>>>(x, r_wv, r_bv, nullptr, rv, M, D, D);
    attn_kernel<<<dim3(S / 64, B * 8), blk, 0, stream>>>(rq, rk, rv, ap, S, D, 8, scale);
    gemm_kernel<true,  false><<<dim3(D / 64, M / 64), blk, 0, stream>>>(ap, r_wo, r_bo, nullptr, ctx, M, D, D);

    // --- affinity -> scores -> top-256 mask ---
    gemm_kernel<true,  false><<<dim3(NI / 64, M / 64), blk, 0, stream>>>(ctx, aff_w, aff_b, nullptr, aff, M, NI, D);
    reduce_stage1<0><<<dim3(NI / 256, 16, B), blk, 0, stream>>>(aff, partial, S, NI);
    reduce_stage2<0><<<dim3(NI / 256, B), blk, 0, stream>>>(partial, scores, NI, 1.0f);
    topk_mask_kernel<512, 256><<<dim3(B), dim3(512), 0, stream>>>(scores, maskI);

    // --- InputNeurons ---
    gemm_kernel<true,  true ><<<dim3(NI / 64, M / 64), blk, 0, stream>>>(ctx, patterns, nullptr, nullptr, act, M, NI, D);
    gemm_kernel<true,  false><<<dim3(NI / 64, M / 64), blk, 0, stream>>>(act, i_wq, i_bq, nullptr, iq, M, NI, NI);
    gemm_kernel<true,  false><<<dim3(NI / 64, M / 64), blk, 0, stream>>>(act, i_wk, i_bk, nullptr, ik, M, NI, NI);
    gemm_kernel<true,  false><<<dim3(NI / 64, M / 64), blk, 0, stream>>>(act, i_wv, i_bv, nullptr, iv, M, NI, NI);
    attn_kernel<<<dim3(S / 64, B * 4), blk, 0, stream>>>(iq, ik, iv, a2p, S, NI, 4, scale);
    gemm_kernel<true,  false><<<dim3(NI / 64, M / 64), blk, 0, stream>>>(a2p, i_wo, i_bo, nullptr, a2f, M, NI, NI);
    ln_mask_kernel<<<dim3(M), blk, 0, stream>>>(act, a2f, ln_g, ln_b, maskI, lnm, NI);

    // --- ProcessNeurons ---
    gemm_kernel<true,  true ><<<dim3(NP / 64, M / 64), blk, 0, stream>>>(lnm, comb_w, nullptr, nullptr, pa, M, NP, NI);
    reduce_stage1<1><<<dim3(NP / 256, 16, B), blk, 0, stream>>>(pa, partial, S, NP);
    reduce_stage2<1><<<dim3(NP / 256, B), blk, 0, stream>>>(partial, ps, NP, 1.0f / 1024.0f);
    topk_mask_kernel<1024, 512><<<dim3(B), dim3(1024), 0, stream>>>(ps, maskP);

    // --- final projection (masked dense) -> d_out ---
    gemm_kernel<false, false><<<dim3(D / 64, M / 64), blk, 0, stream>>>(pa, proj_w, nullptr, maskP, (float*)d_out, M, D, NP);
}

// Round 2
// 1245.845 us; speedup vs baseline: 1.2604x; 1.2604x over previous
//
#include <hip/hip_runtime.h>
#include <math.h>

#define DEVI static __device__ __forceinline__

typedef __attribute__((ext_vector_type(8))) short short8;
typedef __attribute__((ext_vector_type(4))) short short4v;
typedef __attribute__((ext_vector_type(4))) float f32x4;

DEVI float gelu_f(float x) {
    return 0.5f * x * (1.0f + erff(x * 0.7071067811865475f));
}
DEVI unsigned short f2bf(float f) {
    unsigned u = __builtin_bit_cast(unsigned, f);
    unsigned r = (u + 0x7fffu + ((u >> 16) & 1u)) >> 16;
    return (unsigned short)r;
}
DEVI float bf2f(unsigned short b) {
    unsigned u = ((unsigned)b) << 16;
    return __builtin_bit_cast(float, u);
}
DEVI void fmadd4(float4& acc, const float4& a, const float4& b) {
    acc.x = fmaf(a.x, b.x, acc.x);
    acc.y = fmaf(a.y, b.y, acc.y);
    acc.z = fmaf(a.z, b.z, acc.z);
    acc.w = fmaf(a.w, b.w, acc.w);
}
DEVI void fmas4(float4& acc, float p, const float4& v) {
    acc.x = fmaf(p, v.x, acc.x);
    acc.y = fmaf(p, v.y, acc.y);
    acc.z = fmaf(p, v.z, acc.z);
    acc.w = fmaf(p, v.w, acc.w);
}
DEVI float hsum4(const float4& v) { return (v.x + v.y) + (v.z + v.w); }

// ---------------------------------------------------------------------------
// MFMA GEMM, fp32 in/out, bf16x3 split (SPLIT=true) or plain bf16.
// C[M,N] = act( A[M,K] (*amask cols) @ B + bias )
// BT=true: B stored [N,K]; BT=false: B stored [K,N].
// Block: 128 threads (2 waves). Tile 64x64, wave-tile 32(M)x64(N), BK=32.
// LDS rows padded to 40 shorts (80B): fragment reads are 2-way (free).
// ---------------------------------------------------------------------------
template<bool BT, bool DO_GELU, bool SPLIT>
__global__ __launch_bounds__(128)
void gemm_mfma(const float* __restrict__ A, const float* __restrict__ Bm,
               const float* __restrict__ bias, const float* __restrict__ amask,
               float* __restrict__ C, int M, int N, int K)
{
    __shared__ short Ah[64 * 40];
    __shared__ short Al[64 * 40];
    __shared__ short Bh[64 * 40];
    __shared__ short Bl[64 * 40];
    const int t  = threadIdx.x;
    const int w  = t >> 6;         // wave 0..1
    const int l  = t & 63;
    const int lr = l & 15, lg = l >> 4;
    const int m0 = blockIdx.y * 64, n0 = blockIdx.x * 64;

    f32x4 acc[2][4];
    #pragma unroll
    for (int i = 0; i < 2; ++i)
        #pragma unroll
        for (int j = 0; j < 4; ++j) acc[i][j] = 0.0f;

    const int bk = (t >> 4) << 2;  // BT=false staging: k base (0..28)
    const int bn = (t & 15) << 2;  // BT=false staging: n base (0..60)

    for (int k0 = 0; k0 < K; k0 += 32) {
        float4 areg[4], breg[4];
        #pragma unroll
        for (int i = 0; i < 4; ++i) {
            int f = t + i * 128, row = f >> 3, c4 = f & 7;
            areg[i] = *(const float4*)&A[(size_t)(m0 + row) * K + k0 + c4 * 4];
            if (amask) {
                const float* mr = amask + (size_t)((m0 + row) >> 10) * K + k0 + c4 * 4;
                areg[i].x *= mr[0]; areg[i].y *= mr[1];
                areg[i].z *= mr[2]; areg[i].w *= mr[3];
            }
        }
        if (BT) {
            #pragma unroll
            for (int i = 0; i < 4; ++i) {
                int f = t + i * 128, row = f >> 3, c4 = f & 7;
                breg[i] = *(const float4*)&Bm[(size_t)(n0 + row) * K + k0 + c4 * 4];
            }
        } else {
            #pragma unroll
            for (int j = 0; j < 4; ++j)
                breg[j] = *(const float4*)&Bm[(size_t)(k0 + bk + j) * N + n0 + bn];
        }
        __syncthreads();   // previous tile fully consumed
        #pragma unroll
        for (int i = 0; i < 4; ++i) {
            int f = t + i * 128, row = f >> 3, c4 = f & 7;
            const float* av = (const float*)&areg[i];
            short4v hv, lv;
            #pragma unroll
            for (int j = 0; j < 4; ++j) {
                unsigned short hb = f2bf(av[j]);
                hv[j] = (short)hb;
                lv[j] = (short)f2bf(av[j] - bf2f(hb));
            }
            *(short4v*)&Ah[row * 40 + c4 * 4] = hv;
            if (SPLIT) *(short4v*)&Al[row * 40 + c4 * 4] = lv;
        }
        if (BT) {
            #pragma unroll
            for (int i = 0; i < 4; ++i) {
                int f = t + i * 128, row = f >> 3, c4 = f & 7;
                const float* bv = (const float*)&breg[i];
                short4v hv, lv;
                #pragma unroll
                for (int j = 0; j < 4; ++j) {
                    unsigned short hb = f2bf(bv[j]);
                    hv[j] = (short)hb;
                    lv[j] = (short)f2bf(bv[j] - bf2f(hb));
                }
                *(short4v*)&Bh[row * 40 + c4 * 4] = hv;
                if (SPLIT) *(short4v*)&Bl[row * 40 + c4 * 4] = lv;
            }
        } else {
            // transpose 4x4 register block: breg[j] holds B[k0+bk+j][n0+bn..+3]
            #pragma unroll
            for (int jj = 0; jj < 4; ++jj) {
                short4v hv, lv;
                #pragma unroll
                for (int j = 0; j < 4; ++j) {
                    float v = ((const float*)&breg[j])[jj];
                    unsigned short hb = f2bf(v);
                    hv[j] = (short)hb;
                    lv[j] = (short)f2bf(v - bf2f(hb));
                }
                *(short4v*)&Bh[(bn + jj) * 40 + bk] = hv;
                if (SPLIT) *(short4v*)&Bl[(bn + jj) * 40 + bk] = lv;
            }
        }
        __syncthreads();
        short8 ah[2], alo[2], bh[4], blo[4];
        #pragma unroll
        for (int ms = 0; ms < 2; ++ms) {
            ah[ms] = *(const short8*)&Ah[(w * 32 + ms * 16 + lr) * 40 + lg * 8];
            if (SPLIT) alo[ms] = *(const short8*)&Al[(w * 32 + ms * 16 + lr) * 40 + lg * 8];
        }
        #pragma unroll
        for (int ns = 0; ns < 4; ++ns) {
            bh[ns] = *(const short8*)&Bh[(ns * 16 + lr) * 40 + lg * 8];
            if (SPLIT) blo[ns] = *(const short8*)&Bl[(ns * 16 + lr) * 40 + lg * 8];
        }
        #pragma unroll
        for (int ms = 0; ms < 2; ++ms)
            #pragma unroll
            for (int ns = 0; ns < 4; ++ns) {
                acc[ms][ns] = __builtin_amdgcn_mfma_f32_16x16x32_bf16(
                    ah[ms], bh[ns], acc[ms][ns], 0, 0, 0);
                if (SPLIT) {
                    acc[ms][ns] = __builtin_amdgcn_mfma_f32_16x16x32_bf16(
                        ah[ms], blo[ns], acc[ms][ns], 0, 0, 0);
                    acc[ms][ns] = __builtin_amdgcn_mfma_f32_16x16x32_bf16(
                        alo[ms], bh[ns], acc[ms][ns], 0, 0, 0);
                }
            }
    }
    // epilogue: C row = (l>>4)*4 + r, col = l&15 within each 16x16 subtile
    #pragma unroll
    for (int ms = 0; ms < 2; ++ms)
        #pragma unroll
        for (int ns = 0; ns < 4; ++ns) {
            int rrow = m0 + w * 32 + ms * 16 + lg * 4;
            int col  = n0 + ns * 16 + lr;
            float bv = bias ? bias[col] : 0.0f;
            #pragma unroll
            for (int r = 0; r < 4; ++r) {
                float o = acc[ms][ns][r] + bv;
                if (DO_GELU) o = gelu_f(o);
                C[(size_t)(rrow + r) * N + col] = o;
            }
        }
}

// ---------------------------------------------------------------------------
// Streaming MHA (fp32), head_dim=128, S=1024, 32 q-rows per block.
// Scores tiny -> exp without max-subtraction is safe (matches reference math).
// Thread t: row rp=t>>3, key pair {2g,2g+1} / d-cols {32q+4g..+3} (g=t&7).
// ---------------------------------------------------------------------------
__global__ __launch_bounds__(256)
void attn_kernel(const float* __restrict__ Q, const float* __restrict__ K,
                 const float* __restrict__ V, float* __restrict__ O,
                 int S, int Dm, int H, float scale)
{
    __shared__ float Qs[32][132];
    __shared__ float Ks[16][132];
    __shared__ float Vs[16][132];
    __shared__ float Ps[32][17];
    __shared__ float Ls[32];
    const int t  = threadIdx.x;
    const int b  = blockIdx.y / H, h = blockIdx.y % H;
    const int s0 = blockIdx.x * 32;
    const float* Qb = Q + (size_t)b * S * Dm + h * 128;
    const float* Kb = K + (size_t)b * S * Dm + h * 128;
    const float* Vb = V + (size_t)b * S * Dm + h * 128;
    #pragma unroll
    for (int i = 0; i < 4; ++i) {
        int f = t + i * 256;
        int row = f >> 5, c = f & 31;
        *(float4*)&Qs[row][c * 4] = *(const float4*)&Qb[(size_t)(s0 + row) * Dm + c * 4];
    }
    const int rp = t >> 3;
    const int g  = t & 7;
    float4 acc0[4] = {};
    float l0 = 0.f;
    for (int c0 = 0; c0 < S; c0 += 16) {
        __syncthreads();  // previous chunk fully consumed
        #pragma unroll
        for (int i = 0; i < 2; ++i) {
            int f = t + i * 256;
            int row = f >> 5, c = f & 31;
            *(float4*)&Ks[row][c * 4] = *(const float4*)&Kb[(size_t)(c0 + row) * Dm + c * 4];
            *(float4*)&Vs[row][c * 4] = *(const float4*)&Vb[(size_t)(c0 + row) * Dm + c * 4];
        }
        __syncthreads();
        float4 s00 = {}, s01 = {};
        #pragma unroll 8
        for (int d4 = 0; d4 < 32; ++d4) {
            float4 q0 = *(const float4*)&Qs[rp][d4 * 4];
            float4 k0 = *(const float4*)&Ks[2 * g][d4 * 4];
            float4 k1 = *(const float4*)&Ks[2 * g + 1][d4 * 4];
            fmadd4(s00, q0, k0); fmadd4(s01, q0, k1);
        }
        float p00 = __expf(hsum4(s00) * scale);
        float p01 = __expf(hsum4(s01) * scale);
        Ps[rp][2 * g]     = p00;
        Ps[rp][2 * g + 1] = p01;
        l0 += p00 + p01;
        __syncthreads();
        #pragma unroll 4
        for (int j = 0; j < 16; ++j) {
            float pj0 = Ps[rp][j];
            #pragma unroll
            for (int q = 0; q < 4; ++q) {
                float4 v4 = *(const float4*)&Vs[j][q * 32 + g * 4];
                fmas4(acc0[q], pj0, v4);
            }
        }
    }
    #pragma unroll
    for (int off = 1; off < 8; off <<= 1) l0 += __shfl_xor(l0, off, 64);
    if (g == 0) Ls[rp] = l0;
    __syncthreads();
    float inv0 = 1.0f / Ls[rp];
    float* Ob0 = O + (size_t)(b * S + s0 + rp) * Dm + h * 128;
    #pragma unroll
    for (int q = 0; q < 4; ++q) {
        float4 o0;
        o0.x = acc0[q].x * inv0; o0.y = acc0[q].y * inv0;
        o0.z = acc0[q].z * inv0; o0.w = acc0[q].w * inv0;
        *(float4*)&Ob0[q * 32 + g * 4] = o0;
    }
}

// ---------------------------------------------------------------------------
// Reduce over S (axis=1) of X[B,S,N]. OP: 0=max, 1=sum. Two stages.
// ---------------------------------------------------------------------------
template<int OP>
__global__ __launch_bounds__(256)
void reduce_stage1(const float* __restrict__ X, float* __restrict__ P, int S, int N)
{
    int n  = blockIdx.x * 256 + threadIdx.x;
    int sc = blockIdx.y;
    int b  = blockIdx.z;
    const float* base = X + ((size_t)b * S + sc * 64) * N + n;
    float acc = (OP == 0) ? -3.402823466e38f : 0.f;
    for (int s = 0; s < 64; ++s) {
        float v = base[(size_t)s * N];
        acc = (OP == 0) ? fmaxf(acc, v) : (acc + v);
    }
    P[((size_t)b * 16 + sc) * N + n] = acc;
}

template<int OP>
__global__ __launch_bounds__(256)
void reduce_stage2(const float* __restrict__ P, float* __restrict__ Y, int N, float scl)
{
    int n = blockIdx.x * 256 + threadIdx.x;
    int b = blockIdx.y;
    float acc = (OP == 0) ? -3.402823466e38f : 0.f;
    for (int s = 0; s < 16; ++s) {
        float v = P[((size_t)b * 16 + s) * N + n];
        acc = (OP == 0) ? fmaxf(acc, v) : (acc + v);
    }
    Y[(size_t)b * N + n] = (OP == 0) ? acc : acc * scl;
}

// ---------------------------------------------------------------------------
// Top-K -> 0/1 mask. Bitonic sort in LDS (val desc, idx asc) = jax.lax.top_k.
// ---------------------------------------------------------------------------
template<int N, int KSEL>
__global__ __launch_bounds__(1024)
void topk_mask_kernel(const float* __restrict__ Sc, float* __restrict__ mask)
{
    __shared__ float v[N];
    __shared__ int   id[N];
    int t = threadIdx.x;
    int b = blockIdx.x;
    v[t]  = Sc[b * N + t];
    id[t] = t;
    __syncthreads();
    for (int k = 2; k <= N; k <<= 1) {
        for (int j = k >> 1; j > 0; j >>= 1) {
            int ixj = t ^ j;
            if (ixj > t) {
                bool dir = ((t & k) == 0);
                float va = v[t], vb = v[ixj];
                int   ia = id[t], ib = id[ixj];
                bool before_b = (vb > va) || (vb == va && ib < ia);
                bool sw = dir ? before_b : !before_b;
                if (sw) { v[t] = vb; v[ixj] = va; id[t] = ib; id[ixj] = ia; }
            }
            __syncthreads();
        }
    }
    mask[b * N + id[t]] = (t < KSEL) ? 1.0f : 0.0f;
}

// ---------------------------------------------------------------------------
// y = (LayerNorm(x + r) * gamma + beta) * mask[b][n].  N = 512 fixed.
// ---------------------------------------------------------------------------
__global__ __launch_bounds__(256)
void ln_mask_kernel(const float* __restrict__ X, const float* __restrict__ R,
                    const float* __restrict__ gam, const float* __restrict__ bet,
                    const float* __restrict__ mask, float* __restrict__ Y, int N)
{
    int row = blockIdx.x;         // b*S + s, S=1024
    int b   = row >> 10;
    int t   = threadIdx.x;
    const float* x0 = X + (size_t)row * N;
    const float* r0 = R + (size_t)row * N;
    float a1 = x0[t] + r0[t];
    float a2 = x0[t + 256] + r0[t + 256];
    float s  = a1 + a2;
    float sq = a1 * a1 + a2 * a2;
    #pragma unroll
    for (int off = 32; off > 0; off >>= 1) {
        s  += __shfl_down(s, off, 64);
        sq += __shfl_down(sq, off, 64);
    }
    __shared__ float red[8];
    int wid = t >> 6, lane = t & 63;
    if (lane == 0) { red[wid] = s; red[wid + 4] = sq; }
    __syncthreads();
    if (t == 0) {
        float st  = red[0] + red[1] + red[2] + red[3];
        float sqt = red[4] + red[5] + red[6] + red[7];
        float mu  = st / (float)N;
        float var = sqt / (float)N - mu * mu;
        red[0] = mu;
        red[1] = rsqrtf(var + 1e-5f);
    }
    __syncthreads();
    float mu = red[0], rstd = red[1];
    float y1 = (a1 - mu) * rstd * gam[t] + bet[t];
    float y2 = (a2 - mu) * rstd * gam[t + 256] + bet[t + 256];
    Y[(size_t)row * N + t]       = y1 * mask[b * N + t];
    Y[(size_t)row * N + t + 256] = y2 * mask[b * N + t + 256];
}

// ---------------------------------------------------------------------------
extern "C" void kernel_launch(void* const* d_in, const int* in_sizes, int n_in,
                              void* d_out, int out_size, void* d_ws, size_t ws_size,
                              hipStream_t stream)
{
    (void)in_sizes; (void)n_in; (void)out_size; (void)ws_size;
    const float* x        = (const float*)d_in[0];
    const float* r_wq     = (const float*)d_in[1];
    const float* r_wk     = (const float*)d_in[2];
    const float* r_wv     = (const float*)d_in[3];
    const float* r_bq     = (const float*)d_in[4];
    const float* r_bk     = (const float*)d_in[5];
    const float* r_bv     = (const float*)d_in[6];
    const float* r_wo     = (const float*)d_in[7];
    const float* r_bo     = (const float*)d_in[8];
    const float* aff_w    = (const float*)d_in[9];
    const float* aff_b    = (const float*)d_in[10];
    const float* patterns = (const float*)d_in[11];
    const float* i_wq     = (const float*)d_in[12];
    const float* i_wk     = (const float*)d_in[13];
    const float* i_wv     = (const float*)d_in[14];
    const float* i_bq     = (const float*)d_in[15];
    const float* i_bk     = (const float*)d_in[16];
    const float* i_bv     = (const float*)d_in[17];
    const float* i_wo     = (const float*)d_in[18];
    const float* i_bo     = (const float*)d_in[19];
    const float* ln_g     = (const float*)d_in[20];
    const float* ln_b     = (const float*)d_in[21];
    const float* comb_w   = (const float*)d_in[22];
    const float* proj_w   = (const float*)d_in[23];
    // d_in[24]=k_input(256), d_in[25]=k_process(512): hardcoded in templates.

    constexpr int B = 4, S = 1024, D = 1024, NI = 512, NP = 1024;
    constexpr int M = B * S;
    constexpr size_t R4M = 4194304;   // 4M floats
    constexpr size_t R2M = 2097152;

    float* W   = (float*)d_ws;
    float* rq  = W;              // router Q    [4M]  -> later: pa [4M]
    float* rk  = W + R4M;        // router K    [4M]  -> aff[2M] -> iq/ik -> a2f
    float* rv  = W + 2 * R4M;    // router V    [4M]  -> iv[2M], a2p[2M]
    float* ap  = W + 3 * R4M;    // router attn pre-proj [4M] -> act[2M], lnm[2M]
    float* ctx = W + 4 * R4M;    // context     [4M]
    float* aff = rk;             // [B,S,NI] 2M
    float* iq  = rk;             // [2M]
    float* ik  = rk + R2M;       // [2M]
    float* iv  = rv;             // [2M]
    float* a2p = rv + R2M;       // [2M]
    float* a2f = rk;             // [2M] (iq dead by then)
    float* act = ap;             // [2M]
    float* lnm = ap + R2M;       // [2M]
    float* pa  = rq;             // [4M]
    float* sm      = W + 5 * R4M;
    float* partial = sm;                 // up to B*16*1024 = 65536
    float* scores  = sm + 65536;         // B*512
    float* maskI   = sm + 67584;         // B*512
    float* ps      = sm + 69632;         // B*1024
    float* maskP   = sm + 73728;         // B*1024

    const float scale = 0.08838834764831843f;  // 1/sqrt(128)
    dim3 gblk(128);
    dim3 ablk(256);

    // --- DynamicRouter MHA (split precision: feeds selection scores) ---
    gemm_mfma<true,  false, true><<<dim3(D / 64, M / 64), gblk, 0, stream>>>(x, r_wq, r_bq, nullptr, rq, M, D, D);
    gemm_mfma<true,  false, true><<<dim3(D / 64, M / 64), gblk, 0, stream>>>(x, r_wk, r_bk, nullptr, rk, M, D, D);
    gemm_mfma<true,  false, true><<<dim3(D / 64, M / 64), gblk, 0, stream>>>(x, r_wv, r_bv, nullptr, rv, M, D, D);
    attn_kernel<<<dim3(S / 32, B * 8), ablk, 0, stream>>>(rq, rk, rv, ap, S, D, 8, scale);
    gemm_mfma<true,  false, true><<<dim3(D / 64, M / 64), gblk, 0, stream>>>(ap, r_wo, r_bo, nullptr, ctx, M, D, D);

    // --- affinity -> scores -> top-256 mask ---
    gemm_mfma<true,  false, true><<<dim3(NI / 64, M / 64), gblk, 0, stream>>>(ctx, aff_w, aff_b, nullptr, aff, M, NI, D);
    reduce_stage1<0><<<dim3(NI / 256, 16, B), ablk, 0, stream>>>(aff, partial, S, NI);
    reduce_stage2<0><<<dim3(NI / 256, B), ablk, 0, stream>>>(partial, scores, NI, 1.0f);
    topk_mask_kernel<512, 256><<<dim3(B), dim3(512), 0, stream>>>(scores, maskI);

    // --- InputNeurons ---
    gemm_mfma<true,  true,  true><<<dim3(NI / 64, M / 64), gblk, 0, stream>>>(ctx, patterns, nullptr, nullptr, act, M, NI, D);
    gemm_mfma<true,  false, true><<<dim3(NI / 64, M / 64), gblk, 0, stream>>>(act, i_wq, i_bq, nullptr, iq, M, NI, NI);
    gemm_mfma<true,  false, true><<<dim3(NI / 64, M / 64), gblk, 0, stream>>>(act, i_wk, i_bk, nullptr, ik, M, NI, NI);
    gemm_mfma<true,  false, true><<<dim3(NI / 64, M / 64), gblk, 0, stream>>>(act, i_wv, i_bv, nullptr, iv, M, NI, NI);
    attn_kernel<<<dim3(S / 32, B * 4), ablk, 0, stream>>>(iq, ik, iv, a2p, S, NI, 4, scale);
    gemm_mfma<true,  false, true><<<dim3(NI / 64, M / 64), gblk, 0, stream>>>(a2p, i_wo, i_bo, nullptr, a2f, M, NI, NI);
    ln_mask_kernel<<<dim3(M), ablk, 0, stream>>>(act, a2f, ln_g, ln_b, maskI, lnm, NI);

    // --- ProcessNeurons ---
    gemm_mfma<true,  true,  true><<<dim3(NP / 64, M / 64), gblk, 0, stream>>>(lnm, comb_w, nullptr, nullptr, pa, M, NP, NI);
    reduce_stage1<1><<<dim3(NP / 256, 16, B), ablk, 0, stream>>>(pa, partial, S, NP);
    reduce_stage2<1><<<dim3(NP / 256, B), ablk, 0, stream>>>(partial, ps, NP, 1.0f / 1024.0f);
    topk_mask_kernel<1024, 512><<<dim3(B), dim3(1024), 0, stream>>>(ps, maskP);

    // --- final projection (post-selection: plain bf16 is sufficient) ---
    gemm_mfma<false, false, false><<<dim3(D / 64, M / 64), gblk, 0, stream>>>(pa, proj_w, nullptr, maskP, (float*)d_out, M, D, NP);
}

// Round 3
// 790.054 us; speedup vs baseline: 1.9875x; 1.5769x over previous
//
#include <hip/hip_runtime.h>
#include <math.h>

#define DEVI static __device__ __forceinline__

typedef __attribute__((ext_vector_type(8))) short short8;
typedef __attribute__((ext_vector_type(4))) short short4v;
typedef __attribute__((ext_vector_type(4))) float f32x4;
typedef unsigned int u32;

DEVI float gelu_f(float x) {
    return 0.5f * x * (1.0f + erff(x * 0.7071067811865475f));
}
DEVI unsigned short f2bf(float f) {
    unsigned u = __builtin_bit_cast(unsigned, f);
    unsigned r = (u + 0x7fffu + ((u >> 16) & 1u)) >> 16;
    return (unsigned short)r;
}
DEVI float bf2f(unsigned short b) {
    unsigned u = ((unsigned)b) << 16;
    return __builtin_bit_cast(float, u);
}
DEVI u32 pack_hilo(float v) {
    unsigned short hb = f2bf(v);
    unsigned short lb = f2bf(v - bf2f(hb));
    return (u32)hb | ((u32)lb << 16);
}
DEVI void unpack4(uint4 u, short4v& h, short4v& l) {
    h[0] = (short)(u.x & 0xffffu); l[0] = (short)(u.x >> 16);
    h[1] = (short)(u.y & 0xffffu); l[1] = (short)(u.y >> 16);
    h[2] = (short)(u.z & 0xffffu); l[2] = (short)(u.z >> 16);
    h[3] = (short)(u.w & 0xffffu); l[3] = (short)(u.w >> 16);
}
DEVI void unpack8(uint4 a, uint4 b, short8& h, short8& l) {
    const u32 u[8] = {a.x, a.y, a.z, a.w, b.x, b.y, b.z, b.w};
    #pragma unroll
    for (int j = 0; j < 8; ++j) {
        h[j] = (short)(u[j] & 0xffffu);
        l[j] = (short)(u[j] >> 16);
    }
}

// ---------------------------------------------------------------------------
// MFMA GEMM, fp32 in, fp32 or packed-bf16-hi/lo out.
// C[M,N] = act( A[M,K] (*amask cols) @ B + bias )
// BT=true: B stored [N,K]; BT=false: B stored [K,N].
// Block: 128 threads (2 waves). Tile 64x64, wave-tile 32(M)x64(N), BK=32.
// SPLIT=true: bf16x3 error-compensated product (~2^-17 rel err).
// ---------------------------------------------------------------------------
template<bool BT, bool DO_GELU, bool SPLIT, bool PACK_OUT>
__global__ __launch_bounds__(128)
void gemm_mfma(const float* __restrict__ A, const float* __restrict__ Bm,
               const float* __restrict__ bias, const float* __restrict__ amask,
               float* __restrict__ C, int M, int N, int K)
{
    __shared__ short Ah[64 * 40];
    __shared__ short Al[64 * 40];
    __shared__ short Bh[64 * 40];
    __shared__ short Bl[64 * 40];
    const int t  = threadIdx.x;
    const int w  = t >> 6;
    const int l  = t & 63;
    const int lr = l & 15, lg = l >> 4;
    const int m0 = blockIdx.y * 64, n0 = blockIdx.x * 64;

    f32x4 acc[2][4];
    #pragma unroll
    for (int i = 0; i < 2; ++i)
        #pragma unroll
        for (int j = 0; j < 4; ++j) acc[i][j] = 0.0f;

    const int bk = (t >> 4) << 2;
    const int bn = (t & 15) << 2;

    for (int k0 = 0; k0 < K; k0 += 32) {
        float4 areg[4], breg[4];
        #pragma unroll
        for (int i = 0; i < 4; ++i) {
            int f = t + i * 128, row = f >> 3, c4 = f & 7;
            areg[i] = *(const float4*)&A[(size_t)(m0 + row) * K + k0 + c4 * 4];
            if (amask) {
                const float* mr = amask + (size_t)((m0 + row) >> 10) * K + k0 + c4 * 4;
                areg[i].x *= mr[0]; areg[i].y *= mr[1];
                areg[i].z *= mr[2]; areg[i].w *= mr[3];
            }
        }
        if (BT) {
            #pragma unroll
            for (int i = 0; i < 4; ++i) {
                int f = t + i * 128, row = f >> 3, c4 = f & 7;
                breg[i] = *(const float4*)&Bm[(size_t)(n0 + row) * K + k0 + c4 * 4];
            }
        } else {
            #pragma unroll
            for (int j = 0; j < 4; ++j)
                breg[j] = *(const float4*)&Bm[(size_t)(k0 + bk + j) * N + n0 + bn];
        }
        __syncthreads();
        #pragma unroll
        for (int i = 0; i < 4; ++i) {
            int f = t + i * 128, row = f >> 3, c4 = f & 7;
            const float* av = (const float*)&areg[i];
            short4v hv, lv;
            #pragma unroll
            for (int j = 0; j < 4; ++j) {
                unsigned short hb = f2bf(av[j]);
                hv[j] = (short)hb;
                lv[j] = (short)f2bf(av[j] - bf2f(hb));
            }
            *(short4v*)&Ah[row * 40 + c4 * 4] = hv;
            if (SPLIT) *(short4v*)&Al[row * 40 + c4 * 4] = lv;
        }
        if (BT) {
            #pragma unroll
            for (int i = 0; i < 4; ++i) {
                int f = t + i * 128, row = f >> 3, c4 = f & 7;
                const float* bv = (const float*)&breg[i];
                short4v hv, lv;
                #pragma unroll
                for (int j = 0; j < 4; ++j) {
                    unsigned short hb = f2bf(bv[j]);
                    hv[j] = (short)hb;
                    lv[j] = (short)f2bf(bv[j] - bf2f(hb));
                }
                *(short4v*)&Bh[row * 40 + c4 * 4] = hv;
                if (SPLIT) *(short4v*)&Bl[row * 40 + c4 * 4] = lv;
            }
        } else {
            #pragma unroll
            for (int jj = 0; jj < 4; ++jj) {
                short4v hv, lv;
                #pragma unroll
                for (int j = 0; j < 4; ++j) {
                    float v = ((const float*)&breg[j])[jj];
                    unsigned short hb = f2bf(v);
                    hv[j] = (short)hb;
                    lv[j] = (short)f2bf(v - bf2f(hb));
                }
                *(short4v*)&Bh[(bn + jj) * 40 + bk] = hv;
                if (SPLIT) *(short4v*)&Bl[(bn + jj) * 40 + bk] = lv;
            }
        }
        __syncthreads();
        short8 ah[2], alo[2], bh[4], blo[4];
        #pragma unroll
        for (int ms = 0; ms < 2; ++ms) {
            ah[ms] = *(const short8*)&Ah[(w * 32 + ms * 16 + lr) * 40 + lg * 8];
            if (SPLIT) alo[ms] = *(const short8*)&Al[(w * 32 + ms * 16 + lr) * 40 + lg * 8];
        }
        #pragma unroll
        for (int ns = 0; ns < 4; ++ns) {
            bh[ns] = *(const short8*)&Bh[(ns * 16 + lr) * 40 + lg * 8];
            if (SPLIT) blo[ns] = *(const short8*)&Bl[(ns * 16 + lr) * 40 + lg * 8];
        }
        #pragma unroll
        for (int ms = 0; ms < 2; ++ms)
            #pragma unroll
            for (int ns = 0; ns < 4; ++ns) {
                acc[ms][ns] = __builtin_amdgcn_mfma_f32_16x16x32_bf16(
                    ah[ms], bh[ns], acc[ms][ns], 0, 0, 0);
                if (SPLIT) {
                    acc[ms][ns] = __builtin_amdgcn_mfma_f32_16x16x32_bf16(
                        ah[ms], blo[ns], acc[ms][ns], 0, 0, 0);
                    acc[ms][ns] = __builtin_amdgcn_mfma_f32_16x16x32_bf16(
                        alo[ms], bh[ns], acc[ms][ns], 0, 0, 0);
                }
            }
    }
    #pragma unroll
    for (int ms = 0; ms < 2; ++ms)
        #pragma unroll
        for (int ns = 0; ns < 4; ++ns) {
            int rrow = m0 + w * 32 + ms * 16 + lg * 4;
            int col  = n0 + ns * 16 + lr;
            float bv = bias ? bias[col] : 0.0f;
            #pragma unroll
            for (int r = 0; r < 4; ++r) {
                float o = acc[ms][ns][r] + bv;
                if (DO_GELU) o = gelu_f(o);
                if (PACK_OUT)
                    ((u32*)C)[(size_t)(rrow + r) * N + col] = pack_hilo(o);
                else
                    C[(size_t)(rrow + r) * N + col] = o;
            }
        }
}

// ---------------------------------------------------------------------------
// MFMA flash attention, head_dim=128, S=1024, no max-subtraction (scores
// tiny; same math as reference softmax). Inputs Q,K,V are PACKED hi/lo bf16
// (uint32 per element, produced by gemm_mfma<...,PACK_OUT=true>).
// Block: 256 thr / 4 waves; wave owns 16 q-rows; chunk = 32 keys.
// Swapped QK^T (mfma(K,Q) -> S^T) so P-row is lane-local; P split hi/lo and
// staged via LDS in A-frag order; all LDS layouts fragment-ordered with XOR
// bank swizzle (contiguous 16B/lane reads = conflict-free).
// 3-MFMA split products throughout (~2^-17 rel err protects top-k margins).
// ---------------------------------------------------------------------------
__global__ __launch_bounds__(256)
void attn_mfma(const u32* __restrict__ Q, const u32* __restrict__ K,
               const u32* __restrict__ V, float* __restrict__ O,
               int S, int Dm, int H, float scale)
{
    __shared__ short Khi[4096], Klo[4096];   // [T=mt*4+ks][lane][8]
    __shared__ short Vhi[4096], Vlo[4096];   // [Tv=nt][lane][8]
    __shared__ u32   PL[2048];               // per-wave 512, A-frag order
    const int t  = threadIdx.x;
    const int w  = t >> 6, l = t & 63;
    const int lr = l & 15, lg = l >> 4;
    const int b  = blockIdx.y / H, h = blockIdx.y % H;
    const int q0 = blockIdx.x * 64 + w * 16;
    const u32* Qb = Q + (size_t)(b * S) * Dm + h * 128;
    const u32* Kb = K + (size_t)(b * S) * Dm + h * 128;
    const u32* Vb = V + (size_t)(b * S) * Dm + h * 128;

    // Q fragments (B-operand): lane holds col q=lr, k-elems d = ks*32+lg*8+j
    short8 qh[4], ql[4];
    #pragma unroll
    for (int ks = 0; ks < 4; ++ks) {
        const u32* p = &Qb[(size_t)(q0 + lr) * Dm + ks * 32 + lg * 8];
        unpack8(*(const uint4*)p, *(const uint4*)(p + 4), qh[ks], ql[ks]);
    }

    f32x4 accO[8];
    #pragma unroll
    for (int i = 0; i < 8; ++i) accO[i] = 0.0f;
    float ls = 0.0f;

    for (int c0 = 0; c0 < S; c0 += 32) {
        __syncthreads();   // prev chunk fully consumed
        // ---- stage K,V (32 keys x 128 d, packed) into frag-order LDS ----
        #pragma unroll
        for (int i = 0; i < 4; ++i) {
            int u   = i * 256 + t;
            int key = u >> 5;
            int d   = (u & 31) << 2;
            uint4 kv = *(const uint4*)&Kb[(size_t)(c0 + key) * Dm + d];
            int T = ((key >> 4) << 2) + (d >> 5);
            int g = (d >> 3) & 3;
            int sidx = T * 512 + g * 128 + (((key & 15) ^ ((T ^ g) & 15)) << 3) + (d & 7);
            short4v h4, l4;
            unpack4(kv, h4, l4);
            *(short4v*)&Khi[sidx] = h4;
            *(short4v*)&Klo[sidx] = l4;

            uint4 vv = *(const uint4*)&Vb[(size_t)(c0 + key) * Dm + d];
            int gv = (key >> 3) & 3, jv = key & 7;
            int Tv = d >> 4;
            int cb = d & 15;
            const u32* ve = (const u32*)&vv;
            #pragma unroll
            for (int r = 0; r < 4; ++r) {
                int vidx = Tv * 512 + gv * 128 + (((cb + r) ^ ((Tv ^ gv) & 15)) << 3) + jv;
                Vhi[vidx] = (short)(ve[r] & 0xffffu);
                Vlo[vidx] = (short)(ve[r] >> 16);
            }
        }
        __syncthreads();

        // ---- S^T = K . Q^T  (2 m-tiles of 16 keys) ----
        f32x4 sac[2];
        sac[0] = 0.0f; sac[1] = 0.0f;
        #pragma unroll
        for (int ks = 0; ks < 4; ++ks)
            #pragma unroll
            for (int mt = 0; mt < 2; ++mt) {
                int T = mt * 4 + ks;
                int base = T * 512 + lg * 128 + ((lr ^ ((T ^ lg) & 15)) << 3);
                short8 kh = *(const short8*)&Khi[base];
                short8 kl = *(const short8*)&Klo[base];
                sac[mt] = __builtin_amdgcn_mfma_f32_16x16x32_bf16(kh, qh[ks], sac[mt], 0, 0, 0);
                sac[mt] = __builtin_amdgcn_mfma_f32_16x16x32_bf16(kh, ql[ks], sac[mt], 0, 0, 0);
                sac[mt] = __builtin_amdgcn_mfma_f32_16x16x32_bf16(kl, qh[ks], sac[mt], 0, 0, 0);
            }

        // ---- softmax numerator, split, stage P in A-frag order ----
        #pragma unroll
        for (int mt = 0; mt < 2; ++mt)
            #pragma unroll
            for (int rr = 0; rr < 4; ++rr) {
                float p = __expf(sac[mt][rr] * scale);
                ls += p;
                int key = mt * 16 + lg * 4 + rr;
                int gg  = (key >> 3) & 3;
                PL[w * 512 + gg * 128 + ((lr ^ gg) << 3) + (key & 7)] = pack_hilo(p);
            }
        short8 pah, pal;
        {
            int base = w * 512 + lg * 128 + ((lr ^ lg) << 3);
            unpack8(*(const uint4*)&PL[base], *(const uint4*)&PL[base + 4], pah, pal);
        }

        // ---- O += P . V  (8 n-tiles of 16 d) ----
        #pragma unroll
        for (int nt = 0; nt < 8; ++nt) {
            int base = nt * 512 + lg * 128 + ((lr ^ ((nt ^ lg) & 15)) << 3);
            short8 vh = *(const short8*)&Vhi[base];
            short8 vl = *(const short8*)&Vlo[base];
            accO[nt] = __builtin_amdgcn_mfma_f32_16x16x32_bf16(pah, vh, accO[nt], 0, 0, 0);
            accO[nt] = __builtin_amdgcn_mfma_f32_16x16x32_bf16(pah, vl, accO[nt], 0, 0, 0);
            accO[nt] = __builtin_amdgcn_mfma_f32_16x16x32_bf16(pal, vh, accO[nt], 0, 0, 0);
        }
    }

    // ---- normalize and store ----
    float lt = ls + __shfl_xor(ls, 16, 64);
    lt += __shfl_xor(lt, 32, 64);
    float inv[4];
    #pragma unroll
    for (int rr = 0; rr < 4; ++rr) inv[rr] = 1.0f / __shfl(lt, lg * 4 + rr, 64);
    size_t rowb = (size_t)(b * S) + blockIdx.x * 64 + w * 16;
    #pragma unroll
    for (int nt = 0; nt < 8; ++nt)
        #pragma unroll
        for (int rr = 0; rr < 4; ++rr)
            O[(rowb + lg * 4 + rr) * Dm + h * 128 + nt * 16 + lr] = accO[nt][rr] * inv[rr];
}

// ---------------------------------------------------------------------------
// Reduce over S (axis=1) of X[B,S,N]. OP: 0=max, 1=sum. Two stages.
// ---------------------------------------------------------------------------
template<int OP>
__global__ __launch_bounds__(256)
void reduce_stage1(const float* __restrict__ X, float* __restrict__ P, int S, int N)
{
    int n  = blockIdx.x * 256 + threadIdx.x;
    int sc = blockIdx.y;
    int b  = blockIdx.z;
    const float* base = X + ((size_t)b * S + sc * 64) * N + n;
    float acc = (OP == 0) ? -3.402823466e38f : 0.f;
    for (int s = 0; s < 64; ++s) {
        float v = base[(size_t)s * N];
        acc = (OP == 0) ? fmaxf(acc, v) : (acc + v);
    }
    P[((size_t)b * 16 + sc) * N + n] = acc;
}

template<int OP>
__global__ __launch_bounds__(256)
void reduce_stage2(const float* __restrict__ P, float* __restrict__ Y, int N, float scl)
{
    int n = blockIdx.x * 256 + threadIdx.x;
    int b = blockIdx.y;
    float acc = (OP == 0) ? -3.402823466e38f : 0.f;
    for (int s = 0; s < 16; ++s) {
        float v = P[((size_t)b * 16 + s) * N + n];
        acc = (OP == 0) ? fmaxf(acc, v) : (acc + v);
    }
    Y[(size_t)b * N + n] = (OP == 0) ? acc : acc * scl;
}

// ---------------------------------------------------------------------------
// Top-K -> 0/1 mask. Bitonic sort in LDS (val desc, idx asc) = jax.lax.top_k.
// ---------------------------------------------------------------------------
template<int N, int KSEL>
__global__ __launch_bounds__(1024)
void topk_mask_kernel(const float* __restrict__ Sc, float* __restrict__ mask)
{
    __shared__ float v[N];
    __shared__ int   id[N];
    int t = threadIdx.x;
    int b = blockIdx.x;
    v[t]  = Sc[b * N + t];
    id[t] = t;
    __syncthreads();
    for (int k = 2; k <= N; k <<= 1) {
        for (int j = k >> 1; j > 0; j >>= 1) {
            int ixj = t ^ j;
            if (ixj > t) {
                bool dir = ((t & k) == 0);
                float va = v[t], vb = v[ixj];
                int   ia = id[t], ib = id[ixj];
                bool before_b = (vb > va) || (vb == va && ib < ia);
                bool sw = dir ? before_b : !before_b;
                if (sw) { v[t] = vb; v[ixj] = va; id[t] = ib; id[ixj] = ia; }
            }
            __syncthreads();
        }
    }
    mask[b * N + id[t]] = (t < KSEL) ? 1.0f : 0.0f;
}

// ---------------------------------------------------------------------------
// y = (LayerNorm(x + r) * gamma + beta) * mask[b][n].  N = 512 fixed.
// ---------------------------------------------------------------------------
__global__ __launch_bounds__(256)
void ln_mask_kernel(const float* __restrict__ X, const float* __restrict__ R,
                    const float* __restrict__ gam, const float* __restrict__ bet,
                    const float* __restrict__ mask, float* __restrict__ Y, int N)
{
    int row = blockIdx.x;
    int b   = row >> 10;
    int t   = threadIdx.x;
    const float* x0 = X + (size_t)row * N;
    const float* r0 = R + (size_t)row * N;
    float a1 = x0[t] + r0[t];
    float a2 = x0[t + 256] + r0[t + 256];
    float s  = a1 + a2;
    float sq = a1 * a1 + a2 * a2;
    #pragma unroll
    for (int off = 32; off > 0; off >>= 1) {
        s  += __shfl_down(s, off, 64);
        sq += __shfl_down(sq, off, 64);
    }
    __shared__ float red[8];
    int wid = t >> 6, lane = t & 63;
    if (lane == 0) { red[wid] = s; red[wid + 4] = sq; }
    __syncthreads();
    if (t == 0) {
        float st  = red[0] + red[1] + red[2] + red[3];
        float sqt = red[4] + red[5] + red[6] + red[7];
        float mu  = st / (float)N;
        float var = sqt / (float)N - mu * mu;
        red[0] = mu;
        red[1] = rsqrtf(var + 1e-5f);
    }
    __syncthreads();
    float mu = red[0], rstd = red[1];
    float y1 = (a1 - mu) * rstd * gam[t] + bet[t];
    float y2 = (a2 - mu) * rstd * gam[t + 256] + bet[t + 256];
    Y[(size_t)row * N + t]       = y1 * mask[b * N + t];
    Y[(size_t)row * N + t + 256] = y2 * mask[b * N + t + 256];
}

// ---------------------------------------------------------------------------
extern "C" void kernel_launch(void* const* d_in, const int* in_sizes, int n_in,
                              void* d_out, int out_size, void* d_ws, size_t ws_size,
                              hipStream_t stream)
{
    (void)in_sizes; (void)n_in; (void)out_size; (void)ws_size;
    const float* x        = (const float*)d_in[0];
    const float* r_wq     = (const float*)d_in[1];
    const float* r_wk     = (const float*)d_in[2];
    const float* r_wv     = (const float*)d_in[3];
    const float* r_bq     = (const float*)d_in[4];
    const float* r_bk     = (const float*)d_in[5];
    const float* r_bv     = (const float*)d_in[6];
    const float* r_wo     = (const float*)d_in[7];
    const float* r_bo     = (const float*)d_in[8];
    const float* aff_w    = (const float*)d_in[9];
    const float* aff_b    = (const float*)d_in[10];
    const float* patterns = (const float*)d_in[11];
    const float* i_wq     = (const float*)d_in[12];
    const float* i_wk     = (const float*)d_in[13];
    const float* i_wv     = (const float*)d_in[14];
    const float* i_bq     = (const float*)d_in[15];
    const float* i_bk     = (const float*)d_in[16];
    const float* i_bv     = (const float*)d_in[17];
    const float* i_wo     = (const float*)d_in[18];
    const float* i_bo     = (const float*)d_in[19];
    const float* ln_g     = (const float*)d_in[20];
    const float* ln_b     = (const float*)d_in[21];
    const float* comb_w   = (const float*)d_in[22];
    const float* proj_w   = (const float*)d_in[23];

    constexpr int B = 4, S = 1024, D = 1024, NI = 512, NP = 1024;
    constexpr int M = B * S;
    constexpr size_t R4M = 4194304;
    constexpr size_t R2M = 2097152;

    float* W   = (float*)d_ws;
    float* rq  = W;              // router Q packed [4M] -> later: pa [4M]
    float* rk  = W + R4M;        // router K packed [4M] -> aff -> iq/ik -> a2f
    float* rv  = W + 2 * R4M;    // router V packed [4M] -> iv, a2p
    float* ap  = W + 3 * R4M;    // router attn out f32 [4M] -> act, lnm
    float* ctx = W + 4 * R4M;    // context f32 [4M]
    float* aff = rk;
    float* iq  = rk;             // packed
    float* ik  = rk + R2M;       // packed
    float* iv  = rv;             // packed
    float* a2p = rv + R2M;       // f32
    float* a2f = rk;             // f32 (iq dead by then)
    float* act = ap;
    float* lnm = ap + R2M;
    float* pa  = rq;
    float* sm      = W + 5 * R4M;
    float* partial = sm;
    float* scores  = sm + 65536;
    float* maskI   = sm + 67584;
    float* ps      = sm + 69632;
    float* maskP   = sm + 73728;

    const float scale = 0.08838834764831843f;  // 1/sqrt(128)
    dim3 gblk(128);
    dim3 ablk(256);

    // --- DynamicRouter MHA ---
    gemm_mfma<true,  false, true, true ><<<dim3(D / 64, M / 64), gblk, 0, stream>>>(x, r_wq, r_bq, nullptr, rq, M, D, D);
    gemm_mfma<true,  false, true, true ><<<dim3(D / 64, M / 64), gblk, 0, stream>>>(x, r_wk, r_bk, nullptr, rk, M, D, D);
    gemm_mfma<true,  false, true, true ><<<dim3(D / 64, M / 64), gblk, 0, stream>>>(x, r_wv, r_bv, nullptr, rv, M, D, D);
    attn_mfma<<<dim3(S / 64, B * 8), ablk, 0, stream>>>((const u32*)rq, (const u32*)rk, (const u32*)rv, ap, S, D, 8, scale);
    gemm_mfma<true,  false, true, false><<<dim3(D / 64, M / 64), gblk, 0, stream>>>(ap, r_wo, r_bo, nullptr, ctx, M, D, D);

    // --- affinity -> scores -> top-256 mask ---
    gemm_mfma<true,  false, true, false><<<dim3(NI / 64, M / 64), gblk, 0, stream>>>(ctx, aff_w, aff_b, nullptr, aff, M, NI, D);
    reduce_stage1<0><<<dim3(NI / 256, 16, B), ablk, 0, stream>>>(aff, partial, S, NI);
    reduce_stage2<0><<<dim3(NI / 256, B), ablk, 0, stream>>>(partial, scores, NI, 1.0f);
    topk_mask_kernel<512, 256><<<dim3(B), dim3(512), 0, stream>>>(scores, maskI);

    // --- InputNeurons ---
    gemm_mfma<true,  true,  true, false><<<dim3(NI / 64, M / 64), gblk, 0, stream>>>(ctx, patterns, nullptr, nullptr, act, M, NI, D);
    gemm_mfma<true,  false, true, true ><<<dim3(NI / 64, M / 64), gblk, 0, stream>>>(act, i_wq, i_bq, nullptr, iq, M, NI, NI);
    gemm_mfma<true,  false, true, true ><<<dim3(NI / 64, M / 64), gblk, 0, stream>>>(act, i_wk, i_bk, nullptr, ik, M, NI, NI);
    gemm_mfma<true,  false, true, true ><<<dim3(NI / 64, M / 64), gblk, 0, stream>>>(act, i_wv, i_bv, nullptr, iv, M, NI, NI);
    attn_mfma<<<dim3(S / 64, B * 4), ablk, 0, stream>>>((const u32*)iq, (const u32*)ik, (const u32*)iv, a2p, S, NI, 4, scale);
    gemm_mfma<true,  false, true, false><<<dim3(NI / 64, M / 64), gblk, 0, stream>>>(a2p, i_wo, i_bo, nullptr, a2f, M, NI, NI);
    ln_mask_kernel<<<dim3(M), ablk, 0, stream>>>(act, a2f, ln_g, ln_b, maskI, lnm, NI);

    // --- ProcessNeurons ---
    gemm_mfma<true,  true,  true, false><<<dim3(NP / 64, M / 64), gblk, 0, stream>>>(lnm, comb_w, nullptr, nullptr, pa, M, NP, NI);
    reduce_stage1<1><<<dim3(NP / 256, 16, B), ablk, 0, stream>>>(pa, partial, S, NP);
    reduce_stage2<1><<<dim3(NP / 256, B), ablk, 0, stream>>>(partial, ps, NP, 1.0f / 1024.0f);
    topk_mask_kernel<1024, 512><<<dim3(B), dim3(1024), 0, stream>>>(ps, maskP);

    // --- final projection (post-selection: plain bf16 is sufficient) ---
    gemm_mfma<false, false, false, false><<<dim3(D / 64, M / 64), gblk, 0, stream>>>(pa, proj_w, nullptr, maskP, (float*)d_out, M, D, NP);
}

// Round 4
// 641.565 us; speedup vs baseline: 2.4475x; 1.2314x over previous
//
#include <hip/hip_runtime.h>
#include <math.h>

#define DEVI static __device__ __forceinline__

typedef __attribute__((ext_vector_type(8))) short short8;
typedef __attribute__((ext_vector_type(4))) float f32x4;
typedef unsigned short u16;

DEVI float gelu_f(float x) {
    return 0.5f * x * (1.0f + erff(x * 0.7071067811865475f));
}
DEVI u16 f2bf(float f) {
    unsigned u = __builtin_bit_cast(unsigned, f);
    return (u16)((u + 0x7fffu + ((u >> 16) & 1u)) >> 16);
}
DEVI float bf2f(u16 b) {
    unsigned u = ((unsigned)b) << 16;
    return __builtin_bit_cast(float, u);
}
DEVI void split_bf(float v, u16& h, u16& l) {
    h = f2bf(v);
    l = f2bf(v - bf2f(h));
}

// ---------------------------------------------------------------------------
// Plane GEMM: C[M,N] = act( (Ah+Al)[M,K] @ (Bh+Bl)[N,K]^T + bias )
// All operands are bf16 planes (hi, lo). SPLIT: 3-MFMA compensated product.
// OMODE: 0 = f32 out; 1 = planes out; 2 = planes out TRANSPOSED per-head
//        (dst[(b*HH+h)*128+d][1024], for attention V).
// Block: 256 thr / 4 waves, tile 128xBN, BK=64. LDS rows padded to 72 shorts
// (144 B): fragment b128 reads are 2-way bank-aliased (free).
// ---------------------------------------------------------------------------
template<int BN, bool SPLIT, bool DO_GELU, int OMODE>
__global__ __launch_bounds__(256, 2)
void gemm_planes(const u16* __restrict__ Agh, const u16* __restrict__ Agl,
                 const u16* __restrict__ Bgh, const u16* __restrict__ Bgl,
                 const float* __restrict__ bias,
                 float* __restrict__ Cf, u16* __restrict__ Ch, u16* __restrict__ Cl,
                 int M, int N, int K, int HH)
{
    constexpr int BM = 128, BK = 64, PK = 72;
    constexpr int NPL = SPLIT ? 2 : 1;
    constexpr int MF  = (BN == 128) ? 4 : 2;
    __shared__ __align__(16) u16 As[NPL][BM * PK];
    __shared__ __align__(16) u16 Bs[NPL][BN * PK];
    const int t = threadIdx.x, w = t >> 6, l = t & 63;
    const int lr = l & 15, lg = l >> 4;
    const int m0 = blockIdx.y * BM, n0 = blockIdx.x * BN;
    const int moff = (BN == 128) ? (w >> 1) * 64 : w * 32;
    const int noff = (BN == 128) ? (w & 1) * 64 : 0;
    const int srow = t >> 3, sslot = t & 7;

    f32x4 acc[MF][4];
    #pragma unroll
    for (int i = 0; i < MF; ++i)
        #pragma unroll
        for (int j = 0; j < 4; ++j) acc[i][j] = 0.0f;

    for (int k0 = 0; k0 < K; k0 += BK) {
        __syncthreads();   // previous tile fully consumed
        #pragma unroll
        for (int p = 0; p < 4; ++p) {
            int row = p * 32 + srow;
            size_t g = (size_t)(m0 + row) * K + k0 + sslot * 8;
            *(uint4*)&As[0][row * PK + sslot * 8] = *(const uint4*)&Agh[g];
            if constexpr (SPLIT)
                *(uint4*)&As[1][row * PK + sslot * 8] = *(const uint4*)&Agl[g];
        }
        #pragma unroll
        for (int p = 0; p < BN / 32; ++p) {
            int row = p * 32 + srow;
            size_t g = (size_t)(n0 + row) * K + k0 + sslot * 8;
            *(uint4*)&Bs[0][row * PK + sslot * 8] = *(const uint4*)&Bgh[g];
            if constexpr (SPLIT)
                *(uint4*)&Bs[1][row * PK + sslot * 8] = *(const uint4*)&Bgl[g];
        }
        __syncthreads();
        #pragma unroll
        for (int ks = 0; ks < 2; ++ks) {
            short8 af[MF][NPL], bfr[4][NPL];
            #pragma unroll
            for (int mf = 0; mf < MF; ++mf) {
                int a = (moff + mf * 16 + lr) * PK + ks * 32 + lg * 8;
                af[mf][0] = *(const short8*)&As[0][a];
                if constexpr (SPLIT) af[mf][1] = *(const short8*)&As[1][a];
            }
            #pragma unroll
            for (int nf = 0; nf < 4; ++nf) {
                int a = (noff + nf * 16 + lr) * PK + ks * 32 + lg * 8;
                bfr[nf][0] = *(const short8*)&Bs[0][a];
                if constexpr (SPLIT) bfr[nf][1] = *(const short8*)&Bs[1][a];
            }
            #pragma unroll
            for (int mf = 0; mf < MF; ++mf)
                #pragma unroll
                for (int nf = 0; nf < 4; ++nf) {
                    acc[mf][nf] = __builtin_amdgcn_mfma_f32_16x16x32_bf16(
                        af[mf][0], bfr[nf][0], acc[mf][nf], 0, 0, 0);
                    if constexpr (SPLIT) {
                        acc[mf][nf] = __builtin_amdgcn_mfma_f32_16x16x32_bf16(
                            af[mf][0], bfr[nf][1], acc[mf][nf], 0, 0, 0);
                        acc[mf][nf] = __builtin_amdgcn_mfma_f32_16x16x32_bf16(
                            af[mf][1], bfr[nf][0], acc[mf][nf], 0, 0, 0);
                    }
                }
        }
    }
    // epilogue: C row = lg*4+r, col = lr within each 16x16 subtile
    #pragma unroll
    for (int mf = 0; mf < MF; ++mf)
        #pragma unroll
        for (int nf = 0; nf < 4; ++nf) {
            int col  = n0 + noff + nf * 16 + lr;
            int mrow = m0 + moff + mf * 16 + lg * 4;
            float bv = bias ? bias[col] : 0.0f;
            if constexpr (OMODE == 2) {
                ushort4 oh, ol;
                #pragma unroll
                for (int r = 0; r < 4; ++r) {
                    float o = acc[mf][nf][r] + bv;
                    if constexpr (DO_GELU) o = gelu_f(o);
                    u16 hb, lb; split_bf(o, hb, lb);
                    ((u16*)&oh)[r] = hb; ((u16*)&ol)[r] = lb;
                }
                int hh = col >> 7, dd = col & 127;
                int bb = mrow >> 10, s0 = mrow & 1023;
                size_t idx = ((size_t)(bb * HH + hh) * 128 + dd) * 1024 + s0;
                *(ushort4*)&Ch[idx] = oh;
                *(ushort4*)&Cl[idx] = ol;
            } else {
                #pragma unroll
                for (int r = 0; r < 4; ++r) {
                    float o = acc[mf][nf][r] + bv;
                    if constexpr (DO_GELU) o = gelu_f(o);
                    size_t ci = (size_t)(mrow + r) * N + col;
                    if constexpr (OMODE == 0) {
                        Cf[ci] = o;
                    } else {
                        u16 hb, lb; split_bf(o, hb, lb);
                        Ch[ci] = hb; Cl[ci] = lb;
                    }
                }
            }
        }
}

// ---------------------------------------------------------------------------
// Plane flash attention, head_dim=128, S=1024, no max-subtraction (scores
// tiny; same math as reference). Q,K planes [b*S][Dm]; V planes PRE-TRANSPOSED
// [(b*H+h)*128+d][1024]. Output planes [b*S][Dm].
// 4 waves x 16 q-rows; chunk = 32 keys (= one MFMA k-step for PV).
// Swapped QK^T (mfma(K,Q)); P staged hi/lo per-wave in LDS; padded LDS rows
// make all b128 fragment reads <=2-way bank-aliased (free).
// ---------------------------------------------------------------------------
__global__ __launch_bounds__(256, 3)
void attn_planes(const u16* __restrict__ Qh, const u16* __restrict__ Ql,
                 const u16* __restrict__ Kh, const u16* __restrict__ Kl,
                 const u16* __restrict__ Vh, const u16* __restrict__ Vl,
                 u16* __restrict__ Oh, u16* __restrict__ Ol,
                 int S, int Dm, int H, float scale)
{
    __shared__ __align__(16) u16 KsL[2][32 * 136];   // [key][d pad 136]
    __shared__ __align__(16) u16 VsL[2][128 * 40];   // [d][key pad 40]
    __shared__ __align__(16) u16 PsL[2][4 * 16 * 40];// per-wave [q][key pad 40]
    const int t = threadIdx.x, w = t >> 6, l = t & 63;
    const int lr = l & 15, lg = l >> 4;
    const int b = blockIdx.y / H, h = blockIdx.y % H;
    const int q0 = blockIdx.x * 64 + w * 16;
    const size_t qkbase = (size_t)(b * S) * Dm + h * 128;
    const size_t vbase  = (size_t)(b * H + h) * 128 * 1024;

    short8 qhf[4], qlf[4];
    #pragma unroll
    for (int ks = 0; ks < 4; ++ks) {
        size_t g = qkbase + (size_t)(q0 + lr) * Dm + ks * 32 + lg * 8;
        qhf[ks] = *(const short8*)&Qh[g];
        qlf[ks] = *(const short8*)&Ql[g];
    }
    f32x4 accO[8];
    #pragma unroll
    for (int i = 0; i < 8; ++i) accO[i] = 0.0f;
    float ls = 0.0f;
    const int pw = w * 640;   // 16*40 per wave

    for (int c0 = 0; c0 < S; c0 += 32) {
        __syncthreads();   // prev chunk fully consumed
        #pragma unroll
        for (int p = 0; p < 2; ++p) {     // K: 32 keys x 128 d per plane
            int key = p * 16 + (t >> 4);
            int slot = t & 15;
            size_t g = qkbase + (size_t)(c0 + key) * Dm + slot * 8;
            *(uint4*)&KsL[0][key * 136 + slot * 8] = *(const uint4*)&Kh[g];
            *(uint4*)&KsL[1][key * 136 + slot * 8] = *(const uint4*)&Kl[g];
        }
        #pragma unroll
        for (int p = 0; p < 2; ++p) {     // V^T: 128 d x 32 keys per plane
            int d = p * 64 + (t >> 2);
            int ksl = t & 3;
            size_t g = vbase + (size_t)d * 1024 + c0 + ksl * 8;
            *(uint4*)&VsL[0][d * 40 + ksl * 8] = *(const uint4*)&Vh[g];
            *(uint4*)&VsL[1][d * 40 + ksl * 8] = *(const uint4*)&Vl[g];
        }
        __syncthreads();
        // S^T = K . Q^T (2 key-subtiles of 16)
        f32x4 sac[2];
        sac[0] = 0.0f; sac[1] = 0.0f;
        #pragma unroll
        for (int mt = 0; mt < 2; ++mt)
            #pragma unroll
            for (int ks = 0; ks < 4; ++ks) {
                int a = (mt * 16 + lr) * 136 + ks * 32 + lg * 8;
                short8 khf = *(const short8*)&KsL[0][a];
                short8 klf = *(const short8*)&KsL[1][a];
                sac[mt] = __builtin_amdgcn_mfma_f32_16x16x32_bf16(khf, qhf[ks], sac[mt], 0, 0, 0);
                sac[mt] = __builtin_amdgcn_mfma_f32_16x16x32_bf16(khf, qlf[ks], sac[mt], 0, 0, 0);
                sac[mt] = __builtin_amdgcn_mfma_f32_16x16x32_bf16(klf, qhf[ks], sac[mt], 0, 0, 0);
            }
        // P = exp(S*scale), split hi/lo, stage in A-frag order (per-wave LDS)
        #pragma unroll
        for (int mt = 0; mt < 2; ++mt)
            #pragma unroll
            for (int rr = 0; rr < 4; ++rr) {
                float p = __expf(sac[mt][rr] * scale);
                ls += p;
                int key = mt * 16 + lg * 4 + rr;
                u16 hb, lb; split_bf(p, hb, lb);
                PsL[0][pw + lr * 40 + key] = hb;
                PsL[1][pw + lr * 40 + key] = lb;
            }
        short8 pah = *(const short8*)&PsL[0][pw + lr * 40 + lg * 8];
        short8 pal = *(const short8*)&PsL[1][pw + lr * 40 + lg * 8];
        // O += P . V (8 d-subtiles of 16); chunk of 32 keys = one k-step
        #pragma unroll
        for (int nt = 0; nt < 8; ++nt) {
            int a = (nt * 16 + lr) * 40 + lg * 8;
            short8 vhf = *(const short8*)&VsL[0][a];
            short8 vlf = *(const short8*)&VsL[1][a];
            accO[nt] = __builtin_amdgcn_mfma_f32_16x16x32_bf16(pah, vhf, accO[nt], 0, 0, 0);
            accO[nt] = __builtin_amdgcn_mfma_f32_16x16x32_bf16(pah, vlf, accO[nt], 0, 0, 0);
            accO[nt] = __builtin_amdgcn_mfma_f32_16x16x32_bf16(pal, vhf, accO[nt], 0, 0, 0);
        }
    }
    float lt = ls + __shfl_xor(ls, 16, 64);
    lt += __shfl_xor(lt, 32, 64);
    #pragma unroll
    for (int rr = 0; rr < 4; ++rr) {
        float inv = 1.0f / __shfl(lt, lg * 4 + rr, 64);
        size_t rowoff = qkbase + (size_t)(q0 + lg * 4 + rr) * Dm;
        #pragma unroll
        for (int nt = 0; nt < 8; ++nt) {
            float o = accO[nt][rr] * inv;
            u16 hb, lb; split_bf(o, hb, lb);
            Oh[rowoff + nt * 16 + lr] = hb;
            Ol[rowoff + nt * 16 + lr] = lb;
        }
    }
}

// ---------------------------------------------------------------------------
// One-time packers: fp32 -> bf16 hi/lo planes (and transposed variant).
// ---------------------------------------------------------------------------
__global__ __launch_bounds__(256)
void pack_f32(const float* __restrict__ src, u16* __restrict__ dh,
              u16* __restrict__ dl, int n4)
{
    int i = blockIdx.x * 256 + threadIdx.x;
    if (i >= n4) return;
    float4 v = *(const float4*)&src[i * 4];
    ushort4 hv, lv;
    split_bf(v.x, hv.x, lv.x);
    split_bf(v.y, hv.y, lv.y);
    split_bf(v.z, hv.z, lv.z);
    split_bf(v.w, hv.w, lv.w);
    *(ushort4*)&dh[i * 4] = hv;
    *(ushort4*)&dl[i * 4] = lv;
}

__global__ __launch_bounds__(256)
void packT64(const float* __restrict__ src, u16* __restrict__ dh,
             u16* __restrict__ dl, int R, int C)
{
    __shared__ float tile[64][65];
    int r0 = blockIdx.y * 64, c0 = blockIdx.x * 64;
    int t = threadIdx.x;
    #pragma unroll
    for (int i = 0; i < 16; ++i) {
        int idx = i * 256 + t, rr = idx >> 6, cc = idx & 63;
        tile[rr][cc] = src[(size_t)(r0 + rr) * C + c0 + cc];
    }
    __syncthreads();
    #pragma unroll
    for (int i = 0; i < 16; ++i) {
        int idx = i * 256 + t, rr = idx >> 6, cc = idx & 63;
        float v = tile[cc][rr];
        u16 hb, lb; split_bf(v, hb, lb);
        size_t o = (size_t)(c0 + rr) * R + r0 + cc;
        dh[o] = hb; dl[o] = lb;
    }
}

// in-place zero of masked columns of a [4096][1024] hi-plane (mask per batch)
__global__ __launch_bounds__(256)
void mask_rows(u16* __restrict__ ph, const float* __restrict__ mask)
{
    int i = blockIdx.x * 256 + threadIdx.x;
    int i4 = i * 4;
    int bb = i4 >> 20;          // row>>10, row = i4>>10 (N=1024)
    int col = i4 & 1023;
    ushort4 v = *(ushort4*)&ph[i4];
    float4 m = *(const float4*)&mask[bb * 1024 + col];
    if (m.x == 0.f) v.x = 0;
    if (m.y == 0.f) v.y = 0;
    if (m.z == 0.f) v.z = 0;
    if (m.w == 0.f) v.w = 0;
    *(ushort4*)&ph[i4] = v;
}

// ---------------------------------------------------------------------------
// Reductions over S (axis=1). f32 max (affinity) and plane-sum (pa).
// ---------------------------------------------------------------------------
__global__ __launch_bounds__(256)
void reduce_max_f32(const float* __restrict__ X, float* __restrict__ P, int S, int N)
{
    int n = blockIdx.x * 256 + threadIdx.x;
    int sc = blockIdx.y, bb = blockIdx.z;
    const float* base = X + ((size_t)bb * S + sc * 64) * N + n;
    float acc = -3.402823466e38f;
    for (int s = 0; s < 64; ++s) acc = fmaxf(acc, base[(size_t)s * N]);
    P[((size_t)bb * 16 + sc) * N + n] = acc;
}

__global__ __launch_bounds__(256)
void reduce_sum_planes(const u16* __restrict__ Xh, const u16* __restrict__ Xl,
                       float* __restrict__ P, int S, int N)
{
    int n = blockIdx.x * 256 + threadIdx.x;
    int sc = blockIdx.y, bb = blockIdx.z;
    size_t base = ((size_t)bb * S + sc * 64) * N + n;
    float acc = 0.f;
    for (int s = 0; s < 64; ++s)
        acc += bf2f(Xh[base + (size_t)s * N]) + bf2f(Xl[base + (size_t)s * N]);
    P[((size_t)bb * 16 + sc) * N + n] = acc;
}

template<int OP>
__global__ __launch_bounds__(256)
void reduce_stage2(const float* __restrict__ P, float* __restrict__ Y, int N, float scl)
{
    int n = blockIdx.x * 256 + threadIdx.x;
    int bb = blockIdx.y;
    float acc = (OP == 0) ? -3.402823466e38f : 0.f;
    for (int s = 0; s < 16; ++s) {
        float v = P[((size_t)bb * 16 + s) * N + n];
        acc = (OP == 0) ? fmaxf(acc, v) : (acc + v);
    }
    Y[(size_t)bb * N + n] = (OP == 0) ? acc : acc * scl;
}

// ---------------------------------------------------------------------------
// Top-K -> 0/1 mask. Bitonic sort in LDS (val desc, idx asc) = jax.lax.top_k.
// ---------------------------------------------------------------------------
template<int N, int KSEL>
__global__ __launch_bounds__(1024)
void topk_mask_kernel(const float* __restrict__ Sc, float* __restrict__ mask)
{
    __shared__ float v[N];
    __shared__ int   id[N];
    int t = threadIdx.x;
    int b = blockIdx.x;
    v[t]  = Sc[b * N + t];
    id[t] = t;
    __syncthreads();
    for (int k = 2; k <= N; k <<= 1) {
        for (int j = k >> 1; j > 0; j >>= 1) {
            int ixj = t ^ j;
            if (ixj > t) {
                bool dir = ((t & k) == 0);
                float va = v[t], vb = v[ixj];
                int   ia = id[t], ib = id[ixj];
                bool before_b = (vb > va) || (vb == va && ib < ia);
                bool sw = dir ? before_b : !before_b;
                if (sw) { v[t] = vb; v[ixj] = va; id[t] = ib; id[ixj] = ia; }
            }
            __syncthreads();
        }
    }
    mask[b * N + id[t]] = (t < KSEL) ? 1.0f : 0.0f;
}

// ---------------------------------------------------------------------------
// y = (LayerNorm(x + r) * gamma + beta) * mask, plane in / plane out. N=512.
// ---------------------------------------------------------------------------
__global__ __launch_bounds__(256)
void ln_mask_planes(const u16* __restrict__ Xh, const u16* __restrict__ Xl,
                    const u16* __restrict__ Rh, const u16* __restrict__ Rl,
                    const float* __restrict__ gam, const float* __restrict__ bet,
                    const float* __restrict__ mask,
                    u16* __restrict__ Yh, u16* __restrict__ Yl)
{
    int row = blockIdx.x, bb = row >> 10, t = threadIdx.x;
    size_t base = (size_t)row * 512;
    float a1 = bf2f(Xh[base + t]) + bf2f(Xl[base + t])
             + bf2f(Rh[base + t]) + bf2f(Rl[base + t]);
    float a2 = bf2f(Xh[base + t + 256]) + bf2f(Xl[base + t + 256])
             + bf2f(Rh[base + t + 256]) + bf2f(Rl[base + t + 256]);
    float s  = a1 + a2;
    float sq = a1 * a1 + a2 * a2;
    #pragma unroll
    for (int off = 32; off > 0; off >>= 1) {
        s  += __shfl_down(s, off, 64);
        sq += __shfl_down(sq, off, 64);
    }
    __shared__ float red[8];
    int wid = t >> 6, lane = t & 63;
    if (lane == 0) { red[wid] = s; red[wid + 4] = sq; }
    __syncthreads();
    if (t == 0) {
        float st  = red[0] + red[1] + red[2] + red[3];
        float sqt = red[4] + red[5] + red[6] + red[7];
        float mu  = st / 512.0f;
        float var = sqt / 512.0f - mu * mu;
        red[0] = mu;
        red[1] = rsqrtf(var + 1e-5f);
    }
    __syncthreads();
    float mu = red[0], rstd = red[1];
    float y1 = ((a1 - mu) * rstd * gam[t] + bet[t]) * mask[bb * 512 + t];
    float y2 = ((a2 - mu) * rstd * gam[t + 256] + bet[t + 256]) * mask[bb * 512 + t + 256];
    u16 hb, lb;
    split_bf(y1, hb, lb); Yh[base + t] = hb;       Yl[base + t] = lb;
    split_bf(y2, hb, lb); Yh[base + t + 256] = hb; Yl[base + t + 256] = lb;
}

// ---------------------------------------------------------------------------
extern "C" void kernel_launch(void* const* d_in, const int* in_sizes, int n_in,
                              void* d_out, int out_size, void* d_ws, size_t ws_size,
                              hipStream_t stream)
{
    (void)in_sizes; (void)n_in; (void)out_size; (void)ws_size;
    const float* x        = (const float*)d_in[0];
    const float* r_wq     = (const float*)d_in[1];
    const float* r_wk     = (const float*)d_in[2];
    const float* r_wv     = (const float*)d_in[3];
    const float* r_bq     = (const float*)d_in[4];
    const float* r_bk     = (const float*)d_in[5];
    const float* r_bv     = (const float*)d_in[6];
    const float* r_wo     = (const float*)d_in[7];
    const float* r_bo     = (const float*)d_in[8];
    const float* aff_w    = (const float*)d_in[9];
    const float* aff_b    = (const float*)d_in[10];
    const float* patterns = (const float*)d_in[11];
    const float* i_wq     = (const float*)d_in[12];
    const float* i_wk     = (const float*)d_in[13];
    const float* i_wv     = (const float*)d_in[14];
    const float* i_bq     = (const float*)d_in[15];
    const float* i_bk     = (const float*)d_in[16];
    const float* i_bv     = (const float*)d_in[17];
    const float* i_wo     = (const float*)d_in[18];
    const float* i_bo     = (const float*)d_in[19];
    const float* ln_g     = (const float*)d_in[20];
    const float* ln_b     = (const float*)d_in[21];
    const float* comb_w   = (const float*)d_in[22];
    const float* proj_w   = (const float*)d_in[23];

    constexpr size_t MBy = 1024 * 1024;
    constexpr size_t KBy = 1024;
    char* base = (char*)d_ws;

    // pools (lifetimes verified; total 80.4 MB)
    u16* xh   = (u16*)(base + 0 * MBy);   u16* xl   = (u16*)(base + 8 * MBy);
    u16* aph  = xh;                        u16* apl  = xl;
    u16* rqh  = (u16*)(base + 16 * MBy);  u16* rql  = (u16*)(base + 24 * MBy);
    u16* ctxh = rqh;                       u16* ctxl = rql;
    u16* pah  = rqh;                       u16* pal  = rql;
    u16* rkh  = (u16*)(base + 32 * MBy);  u16* rkl  = (u16*)(base + 40 * MBy);
    u16* iqh  = (u16*)(base + 32 * MBy);  u16* iql  = (u16*)(base + 36 * MBy);
    u16* ikh  = (u16*)(base + 40 * MBy);  u16* ikl  = (u16*)(base + 44 * MBy);
    u16* a2fh = (u16*)(base + 32 * MBy);  u16* a2fl = (u16*)(base + 36 * MBy);
    u16* lnmh = (u16*)(base + 40 * MBy);  u16* lnml = (u16*)(base + 44 * MBy);
    u16* rvth = (u16*)(base + 48 * MBy);  u16* rvtl = (u16*)(base + 56 * MBy);
    u16* ivth = (u16*)(base + 48 * MBy);  u16* ivtl = (u16*)(base + 52 * MBy);
    u16* a2ph = (u16*)(base + 56 * MBy);  u16* a2pl = (u16*)(base + 60 * MBy);
    float* aff = (float*)(base + 64 * MBy);
    u16* acth = (u16*)(base + 64 * MBy);  u16* actl = (u16*)(base + 68 * MBy);
    // rotating weight region: 72..80 MB
    u16* wAh  = (u16*)(base + 72 * MBy);  u16* wAl  = (u16*)(base + 74 * MBy);
    u16* awh  = (u16*)(base + 72 * MBy);  u16* awl  = (u16*)(base + 73 * MBy);
    u16* pth  = (u16*)(base + 74 * MBy);  u16* ptl  = (u16*)(base + 75 * MBy);
    u16* iwqh = (u16*)(base + 72 * MBy);  u16* iwql = (u16*)(base + 72 * MBy + 512 * KBy);
    u16* iwkh = (u16*)(base + 73 * MBy);  u16* iwkl = (u16*)(base + 73 * MBy + 512 * KBy);
    u16* iwvh = (u16*)(base + 74 * MBy);  u16* iwvl = (u16*)(base + 74 * MBy + 512 * KBy);
    u16* iwoh = (u16*)(base + 75 * MBy);  u16* iwol = (u16*)(base + 75 * MBy + 512 * KBy);
    u16* cbh  = (u16*)(base + 76 * MBy);  u16* cbl  = (u16*)(base + 77 * MBy);
    u16* pjh  = (u16*)(base + 72 * MBy);  u16* pjl  = (u16*)(base + 74 * MBy);
    float* partial = (float*)(base + 80 * MBy);            // 256 KB
    float* scores  = (float*)(base + 80 * MBy + 256 * KBy);
    float* maskI   = scores + 2048;
    float* ps      = maskI + 2048;
    float* maskP   = ps + 4096;

    const float scale = 0.08838834764831843f;  // 1/sqrt(128)
    dim3 blk(256);
    dim3 g128(8, 32);   // N/128 x M/128
    dim3 g64(8, 32);    // N/64  x M/128

    // --- pack x ---
    pack_f32<<<4096, blk, 0, stream>>>(x, xh, xl, 1048576);

    // --- DynamicRouter MHA (weights packed just-in-time into rotating region) ---
    pack_f32<<<1024, blk, 0, stream>>>(r_wq, wAh, wAl, 262144);
    gemm_planes<128, true, false, 1><<<g128, blk, 0, stream>>>(xh, xl, wAh, wAl, r_bq, nullptr, rqh, rql, 4096, 1024, 1024, 0);
    pack_f32<<<1024, blk, 0, stream>>>(r_wk, wAh, wAl, 262144);
    gemm_planes<128, true, false, 1><<<g128, blk, 0, stream>>>(xh, xl, wAh, wAl, r_bk, nullptr, rkh, rkl, 4096, 1024, 1024, 0);
    pack_f32<<<1024, blk, 0, stream>>>(r_wv, wAh, wAl, 262144);
    gemm_planes<128, true, false, 2><<<g128, blk, 0, stream>>>(xh, xl, wAh, wAl, r_bv, nullptr, rvth, rvtl, 4096, 1024, 1024, 8);
    attn_planes<<<dim3(16, 32), blk, 0, stream>>>(rqh, rql, rkh, rkl, rvth, rvtl, aph, apl, 1024, 1024, 8, scale);
    pack_f32<<<1024, blk, 0, stream>>>(r_wo, wAh, wAl, 262144);
    gemm_planes<128, true, false, 1><<<g128, blk, 0, stream>>>(aph, apl, wAh, wAl, r_bo, nullptr, ctxh, ctxl, 4096, 1024, 1024, 0);

    // --- affinity -> scores -> top-256 mask ---
    pack_f32<<<512, blk, 0, stream>>>(aff_w, awh, awl, 131072);
    pack_f32<<<512, blk, 0, stream>>>(patterns, pth, ptl, 131072);
    gemm_planes<64, true, false, 0><<<g64, blk, 0, stream>>>(ctxh, ctxl, awh, awl, aff_b, aff, nullptr, nullptr, 4096, 512, 1024, 0);
    reduce_max_f32<<<dim3(2, 16, 4), blk, 0, stream>>>(aff, partial, 1024, 512);
    reduce_stage2<0><<<dim3(2, 4), blk, 0, stream>>>(partial, scores, 512, 1.0f);
    topk_mask_kernel<512, 256><<<dim3(4), dim3(512), 0, stream>>>(scores, maskI);

    // --- InputNeurons ---
    gemm_planes<64, true, true, 1><<<g64, blk, 0, stream>>>(ctxh, ctxl, pth, ptl, nullptr, nullptr, acth, actl, 4096, 512, 1024, 0);
    pack_f32<<<256, blk, 0, stream>>>(i_wq, iwqh, iwql, 65536);
    pack_f32<<<256, blk, 0, stream>>>(i_wk, iwkh, iwkl, 65536);
    pack_f32<<<256, blk, 0, stream>>>(i_wv, iwvh, iwvl, 65536);
    pack_f32<<<256, blk, 0, stream>>>(i_wo, iwoh, iwol, 65536);
    gemm_planes<64, true, false, 1><<<g64, blk, 0, stream>>>(acth, actl, iwqh, iwql, i_bq, nullptr, iqh, iql, 4096, 512, 512, 0);
    gemm_planes<64, true, false, 1><<<g64, blk, 0, stream>>>(acth, actl, iwkh, iwkl, i_bk, nullptr, ikh, ikl, 4096, 512, 512, 0);
    gemm_planes<64, true, false, 2><<<g64, blk, 0, stream>>>(acth, actl, iwvh, iwvl, i_bv, nullptr, ivth, ivtl, 4096, 512, 512, 4);
    attn_planes<<<dim3(16, 16), blk, 0, stream>>>(iqh, iql, ikh, ikl, ivth, ivtl, a2ph, a2pl, 1024, 512, 4, scale);
    gemm_planes<64, true, false, 1><<<g64, blk, 0, stream>>>(a2ph, a2pl, iwoh, iwol, i_bo, nullptr, a2fh, a2fl, 4096, 512, 512, 0);
    ln_mask_planes<<<dim3(4096), blk, 0, stream>>>(acth, actl, a2fh, a2fl, ln_g, ln_b, maskI, lnmh, lnml);

    // --- ProcessNeurons ---
    pack_f32<<<512, blk, 0, stream>>>(comb_w, cbh, cbl, 131072);
    packT64<<<dim3(16, 16), blk, 0, stream>>>(proj_w, pjh, pjl, 1024, 1024);
    gemm_planes<128, true, true, 1><<<g128, blk, 0, stream>>>(lnmh, lnml, cbh, cbl, nullptr, nullptr, pah, pal, 4096, 1024, 512, 0);
    reduce_sum_planes<<<dim3(4, 16, 4), blk, 0, stream>>>(pah, pal, partial, 1024, 1024);
    reduce_stage2<1><<<dim3(4, 4), blk, 0, stream>>>(partial, ps, 1024, 1.0f / 1024.0f);
    topk_mask_kernel<1024, 512><<<dim3(4), dim3(1024), 0, stream>>>(ps, maskP);
    mask_rows<<<4096, blk, 0, stream>>>(pah, maskP);

    // --- final projection (post-selection: hi plane only, 1 MFMA) ---
    gemm_planes<128, false, false, 0><<<g128, blk, 0, stream>>>(pah, nullptr, pjh, nullptr, nullptr, (float*)d_out, nullptr, nullptr, 4096, 1024, 1024, 0);
}